// Round 1
// baseline (13177.727 us; speedup 1.0000x reference)
//
#include <hip/hip_runtime.h>
#include <hip/hip_bf16.h>
#include <math.h>

#define BATCH   8
#define NBINS   512
#define BINSZ   10
#define DMODEL  1024
#define NHEAD   8
#define DHEAD   128
#define NLAYER  4
#define NEXP    30
#define TOPK    4
#define SEQ     513            // NBINS + 1
#define NTOK    (BATCH*SEQ)    // 4104
#define NBINTOT (BATCH*NBINS)  // 4096
#define CAPACITY 1152
#define TKF     (NTOK*TOPK)    // 16416

__device__ __forceinline__ float gelu_f(float x) {
  return 0.5f * x * (1.0f + erff(x * 0.7071067811865475f));
}

// ---------------------------------------------------------------- conv frontend
// one block (64 threads) per bin: conv1(1->16,d1) conv2(16->32,d2) conv3(32->64,d4)
// each + BN(eval) + exact GELU, then mean over length -> feat[bin][64]; also msk.
__global__ void conv_frontend(const float* __restrict__ x,
                              const float* __restrict__ w1, const float* __restrict__ w2,
                              const float* __restrict__ w3,
                              const float* __restrict__ g1, const float* __restrict__ b1,
                              const float* __restrict__ g2, const float* __restrict__ b2,
                              const float* __restrict__ g3, const float* __restrict__ b3,
                              float* __restrict__ feat, int* __restrict__ msk) {
  const float bnscale = 0.9999950000374997f;   // 1/sqrt(1+1e-5)
  int bin = blockIdx.x;
  int c = threadIdx.x;
  __shared__ float xs[BINSZ];
  __shared__ float h1[16][BINSZ];
  __shared__ float h2[32][BINSZ];
  if (c < BINSZ) xs[c] = x[bin*BINSZ + c];
  if (c == 0) {
    int all = 1;
    for (int t = 0; t < BINSZ; t++) if (x[bin*BINSZ+t] != -100.0f) { all = 0; break; }
    msk[bin] = all;
  }
  __syncthreads();
  if (c < 16) {
    float sc = g1[c]*bnscale, sh = b1[c];
    float wA = w1[c*3], wB = w1[c*3+1], wC = w1[c*3+2];
    for (int t = 0; t < BINSZ; t++) {
      float acc = wB * xs[t];
      if (t >= 1) acc = fmaf(wA, xs[t-1], acc);
      if (t <= BINSZ-2) acc = fmaf(wC, xs[t+1], acc);
      h1[c][t] = gelu_f(acc*sc + sh);
    }
  }
  __syncthreads();
  if (c < 32) {
    float sc = g2[c]*bnscale, sh = b2[c];
    float acc2[BINSZ];
    for (int t = 0; t < BINSZ; t++) acc2[t] = 0.f;
    for (int ci = 0; ci < 16; ci++) {
      const float* w = w2 + (c*16+ci)*3;
      float wA = w[0], wB = w[1], wC = w[2];
      for (int t = 0; t < BINSZ; t++) {
        float v = wB * h1[ci][t];
        if (t >= 2) v = fmaf(wA, h1[ci][t-2], v);
        if (t <= BINSZ-3) v = fmaf(wC, h1[ci][t+2], v);
        acc2[t] += v;
      }
    }
    for (int t = 0; t < BINSZ; t++) h2[c][t] = gelu_f(acc2[t]*sc + sh);
  }
  __syncthreads();
  {
    float sc = g3[c]*bnscale, sh = b3[c];
    float acc3[BINSZ];
    for (int t = 0; t < BINSZ; t++) acc3[t] = 0.f;
    for (int ci = 0; ci < 32; ci++) {
      const float* w = w3 + (c*32+ci)*3;
      float wA = w[0], wB = w[1], wC = w[2];
      for (int t = 0; t < BINSZ; t++) {
        float v = wB * h2[ci][t];
        if (t >= 4) v = fmaf(wA, h2[ci][t-4], v);
        if (t <= BINSZ-5) v = fmaf(wC, h2[ci][t+4], v);
        acc3[t] += v;
      }
    }
    float mean = 0.f;
    for (int t = 0; t < BINSZ; t++) mean += gelu_f(acc3[t]*sc + sh);
    feat[bin*64 + c] = mean * 0.1f;
  }
}

// ---------------------------------------------------------------- embed + PE
// grid (SEQ, BATCH), 256 threads, 4 cols each.
__global__ void embed_kernel(const float* __restrict__ feat, const int* __restrict__ msk,
                             const float* __restrict__ proj_w, const float* __restrict__ proj_b,
                             const float* __restrict__ cls_token, const float* __restrict__ mask_token,
                             float* __restrict__ h) {
  int s_ = blockIdx.x;
  int b  = blockIdx.y;
  int tid = threadIdx.x;
  __shared__ __align__(16) float fs[64];
  float out[4];
  if (s_ == 0) {
#pragma unroll
    for (int u = 0; u < 4; u++) out[u] = cls_token[tid*4+u];
  } else {
    int bin = b*NBINS + (s_-1);
    if (tid < 16) ((float4*)fs)[tid] = ((const float4*)(feat + (size_t)bin*64))[tid];
    __syncthreads();
    int m_ = msk[bin];
#pragma unroll
    for (int u = 0; u < 4; u++) {
      int d = tid*4+u;
      float acc = proj_b[d];
      for (int ci = 0; ci < 64; ci++) acc = fmaf(fs[ci], proj_w[ci*DMODEL + d], acc);
      out[u] = m_ ? mask_token[d] : acc;
    }
  }
  const float c0 = -0.008994473019507992f;  // -ln(10000)/1024
#pragma unroll
  for (int u = 0; u < 4; u++) {
    int d = tid*4+u;
    float div = expf(c0 * (float)(d & ~1));
    float ang = (float)s_ * div;
    float pe = (d & 1) ? cosf(ang) : sinf(ang);
    h[((size_t)(b*SEQ + s_))*DMODEL + d] = out[u] + pe;
  }
}

// ---------------------------------------------------------------- layernorm
__global__ void ln_kernel(const float* __restrict__ x, float* __restrict__ out,
                          const float* __restrict__ g, const float* __restrict__ b) {
  int t = blockIdx.x, tid = threadIdx.x;
  float4 v = ((const float4*)(x + (size_t)t*DMODEL))[tid];
  float s  = v.x+v.y+v.z+v.w;
  float sq = v.x*v.x+v.y*v.y+v.z*v.z+v.w*v.w;
  for (int off = 32; off; off >>= 1) { s += __shfl_down(s, off); sq += __shfl_down(sq, off); }
  __shared__ float ss[4], ssq[4], mv[2];
  int w = tid >> 6, l = tid & 63;
  if (l == 0) { ss[w] = s; ssq[w] = sq; }
  __syncthreads();
  if (tid == 0) {
    float a = 0, c = 0;
    for (int i = 0; i < 4; i++) { a += ss[i]; c += ssq[i]; }
    float mean = a * (1.f/DMODEL);
    float var  = c * (1.f/DMODEL) - mean*mean;
    mv[0] = mean; mv[1] = rsqrtf(var + 1e-5f);
  }
  __syncthreads();
  float mean = mv[0], inv = mv[1];
  float4 gg = ((const float4*)g)[tid];
  float4 bb = ((const float4*)b)[tid];
  float4 o;
  o.x = (v.x-mean)*inv*gg.x + bb.x;
  o.y = (v.y-mean)*inv*gg.y + bb.y;
  o.z = (v.z-mean)*inv*gg.z + bb.z;
  o.w = (v.w-mean)*inv*gg.w + bb.w;
  ((float4*)(out + (size_t)t*DMODEL))[tid] = o;
}

// ---------------------------------------------------------------- fp32 GEMM, N=1024, K=1024
// MODE 0: C[r] = A[r]@W + bias                    (QKV)
// MODE 1: C[r] += A[r]@W + bias                   (WO residual)
// MODE 2: MoE ffn1: gather A row = token(f), out hid[f] = gelu(...), bias per-expert
// MODE 3: MoE ffn2: gather A row = hid[f], out y[f] = gate[f]*(...), bias per-expert
template<int MODE>
__global__ __launch_bounds__(256) void gemm_f32(
    const float* __restrict__ A, const float* __restrict__ W,
    const float* __restrict__ bias, float* __restrict__ C, int M,
    const int* __restrict__ rowmap, const int* __restrict__ cnt,
    const float* __restrict__ gate) {
  const int Kd = 1024;
  int tid = threadIdx.x;
  int tx = tid & 15, ty = tid >> 4;
  int rowbase, validrows, e = 0;
  const float* Wb = W;
  if (MODE <= 1) {
    rowbase = blockIdx.x * 64;
    validrows = M - rowbase; if (validrows > 64) validrows = 64;
  } else {
    e = blockIdx.x / 18;
    int p0 = (blockIdx.x % 18) * 64;
    int ce = cnt[e];
    if (p0 >= ce) return;
    rowbase = p0;
    validrows = ce - p0; if (validrows > 64) validrows = 64;
    Wb = W + (size_t)e * Kd * 1024;
  }
  int colbase = blockIdx.y * 64;

  __shared__ __align__(16) float As[16][68];
  __shared__ __align__(16) float Ws[16][64];
  __shared__ int srcrow[64];
  __shared__ int frow[64];

  if (tid < 64) {
    if (MODE <= 1) { srcrow[tid] = rowbase + tid; frow[tid] = rowbase + tid; }
    else if (tid < validrows) {
      int f = rowmap[e*CAPACITY + rowbase + tid];
      frow[tid] = f;
      srcrow[tid] = (MODE == 2) ? (f >> 2) : f;
    } else { frow[tid] = 0; srcrow[tid] = 0; }
  }
  __syncthreads();

  float acc[4][4] = {};
  int arow = tid >> 2;
  int ak0  = (tid & 3) << 2;
  int wk   = tid >> 4;
  int wc0  = (tid & 15) << 2;
  const float* Aptr = A + (size_t)srcrow[arow] * Kd;
  bool aval = (arow < validrows);
  const float* Wptr = Wb + (size_t)wk * 1024 + colbase + wc0;

  for (int kt = 0; kt < Kd; kt += 16) {
    float4 av = make_float4(0.f, 0.f, 0.f, 0.f);
    if (aval) av = *(const float4*)(Aptr + kt + ak0);
    As[ak0+0][arow] = av.x;
    As[ak0+1][arow] = av.y;
    As[ak0+2][arow] = av.z;
    As[ak0+3][arow] = av.w;
    *(float4*)&Ws[wk][wc0] = *(const float4*)(Wptr + (size_t)kt * 1024);
    __syncthreads();
#pragma unroll
    for (int kk = 0; kk < 16; kk++) {
      const float4 a4 = *(const float4*)&As[kk][ty << 2];
      const float4 w4 = *(const float4*)&Ws[kk][tx << 2];
      const float avr[4] = {a4.x, a4.y, a4.z, a4.w};
      const float wvr[4] = {w4.x, w4.y, w4.z, w4.w};
#pragma unroll
      for (int i = 0; i < 4; i++)
#pragma unroll
        for (int j = 0; j < 4; j++)
          acc[i][j] = fmaf(avr[i], wvr[j], acc[i][j]);
    }
    __syncthreads();
  }

  const float* bptr = (MODE >= 2) ? (bias + (size_t)e * 1024) : bias;
  float4 b4 = *(const float4*)(bptr + colbase + (tx << 2));
#pragma unroll
  for (int i = 0; i < 4; i++) {
    int r = (ty << 2) + i;
    if (r >= validrows) continue;
    float v0 = acc[i][0] + b4.x, v1 = acc[i][1] + b4.y;
    float v2 = acc[i][2] + b4.z, v3 = acc[i][3] + b4.w;
    if (MODE == 0) {
      *(float4*)(C + (size_t)(rowbase+r)*1024 + colbase + (tx<<2)) = make_float4(v0,v1,v2,v3);
    } else if (MODE == 1) {
      float4* p = (float4*)(C + (size_t)(rowbase+r)*1024 + colbase + (tx<<2));
      float4 old = *p;
      *p = make_float4(old.x+v0, old.y+v1, old.z+v2, old.w+v3);
    } else if (MODE == 2) {
      *(float4*)(C + (size_t)frow[r]*1024 + colbase + (tx<<2)) =
          make_float4(gelu_f(v0), gelu_f(v1), gelu_f(v2), gelu_f(v3));
    } else {
      float gv = gate[frow[r]];
      *(float4*)(C + (size_t)frow[r]*1024 + colbase + (tx<<2)) =
          make_float4(gv*v0, gv*v1, gv*v2, gv*v3);
    }
  }
}

// ---------------------------------------------------------------- attention
// one block per (q row, b*h). scores -> softmax -> PV, all in LDS/regs.
__global__ __launch_bounds__(256) void attn_kernel(const float* __restrict__ q,
                                                   const float* __restrict__ k,
                                                   const float* __restrict__ v,
                                                   float* __restrict__ o) {
  int qi = blockIdx.x;
  int bh = blockIdx.y;
  int b = bh >> 3, hh = bh & 7;
  int tid = threadIdx.x;
  __shared__ __align__(16) float qs[DHEAD];
  __shared__ float s[SEQ];
  __shared__ float red[4], red2[4], bro[2];
  const float* qrow = q + ((size_t)(b*SEQ + qi))*DMODEL + hh*DHEAD;
  if (tid < 32) ((float4*)qs)[tid] = ((const float4*)qrow)[tid];
  __syncthreads();
  const float scale = 0.08838834764831845f;  // 1/sqrt(128)
  for (int kk = tid; kk < SEQ; kk += 256) {
    const float* krow = k + ((size_t)(b*SEQ + kk))*DMODEL + hh*DHEAD;
    float acc = 0.f;
    for (int d = 0; d < DHEAD; d += 4) {
      float4 kv = *(const float4*)(krow + d);
      acc = fmaf(qs[d], kv.x, acc);
      acc = fmaf(qs[d+1], kv.y, acc);
      acc = fmaf(qs[d+2], kv.z, acc);
      acc = fmaf(qs[d+3], kv.w, acc);
    }
    s[kk] = acc * scale;
  }
  __syncthreads();
  float mx = -1e30f;
  for (int kk = tid; kk < SEQ; kk += 256) mx = fmaxf(mx, s[kk]);
  for (int off = 32; off; off >>= 1) mx = fmaxf(mx, __shfl_down(mx, off));
  if ((tid & 63) == 0) red[tid >> 6] = mx;
  __syncthreads();
  if (tid == 0) {
    float m2 = red[0];
    for (int i = 1; i < 4; i++) m2 = fmaxf(m2, red[i]);
    bro[0] = m2;
  }
  __syncthreads();
  mx = bro[0];
  float sum = 0.f;
  for (int kk = tid; kk < SEQ; kk += 256) { float e_ = expf(s[kk]-mx); s[kk] = e_; sum += e_; }
  for (int off = 32; off; off >>= 1) sum += __shfl_down(sum, off);
  if ((tid & 63) == 0) red2[tid >> 6] = sum;
  __syncthreads();
  if (tid == 0) { bro[1] = red2[0]+red2[1]+red2[2]+red2[3]; }
  __syncthreads();
  float inv = 1.f / bro[1];
  if (tid < DHEAD) {
    float acc = 0.f;
    const float* vbase = v + ((size_t)(b*SEQ))*DMODEL + hh*DHEAD + tid;
    for (int kk = 0; kk < SEQ; kk++) acc = fmaf(s[kk], vbase[(size_t)kk*DMODEL], acc);
    o[((size_t)(b*SEQ + qi))*DMODEL + hh*DHEAD + tid] = acc * inv;
  }
}

// ---------------------------------------------------------------- MoE gating (softmax + top-4)
__global__ void moe_gate(const float* __restrict__ m, const float* __restrict__ wg,
                         const float* __restrict__ bg, int* __restrict__ idx,
                         float* __restrict__ gate) {
  int t = blockIdx.x, tid = threadIdx.x;
  __shared__ __align__(16) float xs[DMODEL];
  __shared__ float probs[32];
  ((float4*)xs)[tid] = ((const float4*)(m + (size_t)t*DMODEL))[tid];
  __syncthreads();
  int e = tid >> 3, sub = tid & 7;
  if (e < NEXP) {
    float p = 0.f;
    for (int d = sub; d < DMODEL; d += 8) p = fmaf(xs[d], wg[d*NEXP + e], p);
    p += __shfl_down(p, 4, 8);
    p += __shfl_down(p, 2, 8);
    p += __shfl_down(p, 1, 8);
    if (sub == 0) probs[e] = p + bg[e];
  }
  __syncthreads();
  if (tid == 0) {
    float mx = probs[0];
    for (int i = 1; i < NEXP; i++) mx = fmaxf(mx, probs[i]);
    float ssum = 0.f;
    for (int i = 0; i < NEXP; i++) { probs[i] = expf(probs[i]-mx); ssum += probs[i]; }
    float invs = 1.f / ssum;
    float gv[TOPK]; int gi[TOPK]; float gsum = 0.f;
    for (int kk = 0; kk < TOPK; kk++) {
      float best = -1.f; int bi = 0;
      for (int i = 0; i < NEXP; i++) if (probs[i] > best) { best = probs[i]; bi = i; }
      gv[kk] = best * invs; gi[kk] = bi; probs[bi] = -1.f; gsum += gv[kk];
    }
    float ginv = 1.f / gsum;
    for (int kk = 0; kk < TOPK; kk++) { idx[t*TOPK+kk] = gi[kk]; gate[t*TOPK+kk] = gv[kk]*ginv; }
  }
}

// ---------------------------------------------------------------- MoE dispatch (capacity scan)
// one block per expert; block-wide prefix scan over 16416 flat slots in order.
__global__ void moe_dispatch(const int* __restrict__ idx, int* __restrict__ slot,
                             int* __restrict__ rowmap, int* __restrict__ cnt) {
  int e = blockIdx.x, tid = threadIdx.x;
  __shared__ int scan[256];
  int base = 0;
  for (int c0 = 0; c0 < TKF; c0 += 256) {
    int f = c0 + tid;
    int match = (f < TKF && idx[f] == e) ? 1 : 0;
    scan[tid] = match;
    __syncthreads();
    for (int off = 1; off < 256; off <<= 1) {
      int vv = (tid >= off) ? scan[tid-off] : 0;
      __syncthreads();
      scan[tid] += vv;
      __syncthreads();
    }
    int incl = scan[tid];
    int total = scan[255];
    if (match) {
      int pos = base + incl - 1;
      if (pos < CAPACITY) { slot[f] = pos; rowmap[e*CAPACITY + pos] = f; }
      else slot[f] = -1;
    }
    base += total;
    __syncthreads();
  }
  if (tid == 0) cnt[e] = (base < CAPACITY) ? base : CAPACITY;
}

// ---------------------------------------------------------------- MoE combine
__global__ void moe_sum(const float* __restrict__ y, const int* __restrict__ slot,
                        float* __restrict__ h) {
  int t = blockIdx.x, d4 = threadIdx.x;
  float4 acc = ((float4*)(h + (size_t)t*DMODEL))[d4];
#pragma unroll
  for (int kk = 0; kk < TOPK; kk++) {
    int f = t*TOPK + kk;
    if (slot[f] >= 0) {
      float4 yv = ((const float4*)(y + (size_t)f*DMODEL))[d4];
      acc.x += yv.x; acc.y += yv.y; acc.z += yv.z; acc.w += yv.w;
    }
  }
  ((float4*)(h + (size_t)t*DMODEL))[d4] = acc;
}

// ---------------------------------------------------------------- final output
__global__ void final_copy(const float* __restrict__ h, float* __restrict__ out) {
  int b = blockIdx.x, tid = threadIdx.x;
  float4 v = ((const float4*)(h + (size_t)b*SEQ*DMODEL))[tid];
  ((float4*)(out + (size_t)b*DMODEL))[tid] = v;
}

// ---------------------------------------------------------------- host
extern "C" void kernel_launch(void* const* d_in, const int* in_sizes, int n_in,
                              void* d_out, int out_size, void* d_ws, size_t ws_size,
                              hipStream_t stream) {
  (void)in_sizes; (void)n_in; (void)out_size; (void)ws_size;
  const float* x         = (const float*)d_in[0];
  const float* conv_w1   = (const float*)d_in[1];
  const float* conv_w2   = (const float*)d_in[2];
  const float* conv_w3   = (const float*)d_in[3];
  const float* bn1_g     = (const float*)d_in[4];
  const float* bn1_b     = (const float*)d_in[5];
  const float* bn2_g     = (const float*)d_in[6];
  const float* bn2_b     = (const float*)d_in[7];
  const float* bn3_g     = (const float*)d_in[8];
  const float* bn3_b     = (const float*)d_in[9];
  const float* proj_w    = (const float*)d_in[10];
  const float* proj_b    = (const float*)d_in[11];
  const float* cls_token = (const float*)d_in[12];
  const float* mask_tok  = (const float*)d_in[13];
  const float* ln1_g     = (const float*)d_in[14];
  const float* ln1_b     = (const float*)d_in[15];
  const float* ln2_g     = (const float*)d_in[16];
  const float* ln2_b     = (const float*)d_in[17];
  const float* wq        = (const float*)d_in[18];
  const float* wk        = (const float*)d_in[19];
  const float* wv        = (const float*)d_in[20];
  const float* wo        = (const float*)d_in[21];
  const float* bq        = (const float*)d_in[22];
  const float* bk        = (const float*)d_in[23];
  const float* bv        = (const float*)d_in[24];
  const float* bo        = (const float*)d_in[25];
  const float* wg        = (const float*)d_in[26];
  const float* bg        = (const float*)d_in[27];
  const float* we1       = (const float*)d_in[28];
  const float* be1       = (const float*)d_in[29];
  const float* we2       = (const float*)d_in[30];
  const float* be2       = (const float*)d_in[31];
  float* out = (float*)d_out;

  float* ws = (float*)d_ws;
  const size_t TD = (size_t)NTOK * DMODEL;   // 4,202,496 floats
  float* h    = ws;
  float* xbuf = ws + TD;
  float* qb   = ws + 2*TD;
  float* kb   = ws + 3*TD;
  float* vb   = ws + 4*TD;
  float* ao   = ws + 5*TD;
  float* hid  = ws + 2*TD;          // aliases qb..ao (TKF*1024 == 4*TD), safe: used after attn+WO
  float* yb   = ws + 6*TD;          // 4*TD
  float* feat = ws + 10*TD;         // NBINTOT*64
  float* gate = feat + (size_t)NBINTOT*64;
  int* idx    = (int*)(gate + TKF);
  int* slot   = idx + TKF;
  int* rowmap = slot + TKF;
  int* cnt    = rowmap + NEXP*CAPACITY;
  int* msk    = cnt + 32;

  conv_frontend<<<NBINTOT, 64, 0, stream>>>(x, conv_w1, conv_w2, conv_w3,
      bn1_g, bn1_b, bn2_g, bn2_b, bn3_g, bn3_b, feat, msk);
  embed_kernel<<<dim3(SEQ, BATCH), 256, 0, stream>>>(feat, msk, proj_w, proj_b,
      cls_token, mask_tok, h);

  dim3 gdense((NTOK + 63)/64, 16);       // 65 x 16
  dim3 gmoe(NEXP*18, 16);                // 540 x 16

  for (int l = 0; l < NLAYER; l++) {
    const float* wq_l = wq + (size_t)l*DMODEL*DMODEL;
    const float* wk_l = wk + (size_t)l*DMODEL*DMODEL;
    const float* wv_l = wv + (size_t)l*DMODEL*DMODEL;
    const float* wo_l = wo + (size_t)l*DMODEL*DMODEL;
    const float* we1_l = we1 + (size_t)l*NEXP*DMODEL*1024;
    const float* we2_l = we2 + (size_t)l*NEXP*1024*DMODEL;

    ln_kernel<<<NTOK, 256, 0, stream>>>(h, xbuf, ln1_g + (size_t)l*DMODEL, ln1_b + (size_t)l*DMODEL);
    gemm_f32<0><<<gdense, 256, 0, stream>>>(xbuf, wq_l, bq + (size_t)l*DMODEL, qb, NTOK, nullptr, nullptr, nullptr);
    gemm_f32<0><<<gdense, 256, 0, stream>>>(xbuf, wk_l, bk + (size_t)l*DMODEL, kb, NTOK, nullptr, nullptr, nullptr);
    gemm_f32<0><<<gdense, 256, 0, stream>>>(xbuf, wv_l, bv + (size_t)l*DMODEL, vb, NTOK, nullptr, nullptr, nullptr);
    attn_kernel<<<dim3(SEQ, BATCH*NHEAD), 256, 0, stream>>>(qb, kb, vb, ao);
    gemm_f32<1><<<gdense, 256, 0, stream>>>(ao, wo_l, bo + (size_t)l*DMODEL, h, NTOK, nullptr, nullptr, nullptr);
    ln_kernel<<<NTOK, 256, 0, stream>>>(h, xbuf, ln2_g + (size_t)l*DMODEL, ln2_b + (size_t)l*DMODEL);
    moe_gate<<<NTOK, 256, 0, stream>>>(xbuf, wg + (size_t)l*DMODEL*NEXP, bg + (size_t)l*NEXP, idx, gate);
    moe_dispatch<<<NEXP, 256, 0, stream>>>(idx, slot, rowmap, cnt);
    gemm_f32<2><<<gmoe, 256, 0, stream>>>(xbuf, we1_l, be1 + (size_t)l*NEXP*1024, hid, 0, rowmap, cnt, nullptr);
    gemm_f32<3><<<gmoe, 256, 0, stream>>>(hid, we2_l, be2 + (size_t)l*NEXP*1024, yb, 0, rowmap, cnt, gate);
    moe_sum<<<NTOK, 256, 0, stream>>>(yb, slot, h);
  }
  final_copy<<<BATCH, 256, 0, stream>>>(h, out);
}

// Round 2
// 5273.033 us; speedup vs baseline: 2.4991x; 2.4991x over previous
//
#include <hip/hip_runtime.h>
#include <hip/hip_bf16.h>
#include <math.h>

#define BATCH   8
#define NBINS   512
#define BINSZ   10
#define DMODEL  1024
#define NHEAD   8
#define DHEAD   128
#define NLAYER  4
#define NEXP    30
#define TOPK    4
#define SEQ     513            // NBINS + 1
#define NTOK    (BATCH*SEQ)    // 4104
#define NBINTOT (BATCH*NBINS)  // 4096
#define CAPACITY 1152
#define TKF     (NTOK*TOPK)    // 16416

typedef __attribute__((ext_vector_type(8))) __bf16 bf16x8;
typedef __attribute__((ext_vector_type(4))) float f32x4;

__device__ __forceinline__ float gelu_f(float x) {
  return 0.5f * x * (1.0f + erff(x * 0.7071067811865475f));
}

// ---------------------------------------------------------------- conv frontend
__global__ void conv_frontend(const float* __restrict__ x,
                              const float* __restrict__ w1, const float* __restrict__ w2,
                              const float* __restrict__ w3,
                              const float* __restrict__ g1, const float* __restrict__ b1,
                              const float* __restrict__ g2, const float* __restrict__ b2,
                              const float* __restrict__ g3, const float* __restrict__ b3,
                              float* __restrict__ feat, int* __restrict__ msk) {
  const float bnscale = 0.9999950000374997f;   // 1/sqrt(1+1e-5)
  int bin = blockIdx.x;
  int c = threadIdx.x;
  __shared__ float xs[BINSZ];
  __shared__ float h1[16][BINSZ];
  __shared__ float h2[32][BINSZ];
  if (c < BINSZ) xs[c] = x[bin*BINSZ + c];
  if (c == 0) {
    int all = 1;
    for (int t = 0; t < BINSZ; t++) if (x[bin*BINSZ+t] != -100.0f) { all = 0; break; }
    msk[bin] = all;
  }
  __syncthreads();
  if (c < 16) {
    float sc = g1[c]*bnscale, sh = b1[c];
    float wA = w1[c*3], wB = w1[c*3+1], wC = w1[c*3+2];
    for (int t = 0; t < BINSZ; t++) {
      float acc = wB * xs[t];
      if (t >= 1) acc = fmaf(wA, xs[t-1], acc);
      if (t <= BINSZ-2) acc = fmaf(wC, xs[t+1], acc);
      h1[c][t] = gelu_f(acc*sc + sh);
    }
  }
  __syncthreads();
  if (c < 32) {
    float sc = g2[c]*bnscale, sh = b2[c];
    float acc2[BINSZ];
    for (int t = 0; t < BINSZ; t++) acc2[t] = 0.f;
    for (int ci = 0; ci < 16; ci++) {
      const float* w = w2 + (c*16+ci)*3;
      float wA = w[0], wB = w[1], wC = w[2];
      for (int t = 0; t < BINSZ; t++) {
        float v = wB * h1[ci][t];
        if (t >= 2) v = fmaf(wA, h1[ci][t-2], v);
        if (t <= BINSZ-3) v = fmaf(wC, h1[ci][t+2], v);
        acc2[t] += v;
      }
    }
    for (int t = 0; t < BINSZ; t++) h2[c][t] = gelu_f(acc2[t]*sc + sh);
  }
  __syncthreads();
  {
    float sc = g3[c]*bnscale, sh = b3[c];
    float acc3[BINSZ];
    for (int t = 0; t < BINSZ; t++) acc3[t] = 0.f;
    for (int ci = 0; ci < 32; ci++) {
      const float* w = w3 + (c*32+ci)*3;
      float wA = w[0], wB = w[1], wC = w[2];
      for (int t = 0; t < BINSZ; t++) {
        float v = wB * h2[ci][t];
        if (t >= 4) v = fmaf(wA, h2[ci][t-4], v);
        if (t <= BINSZ-5) v = fmaf(wC, h2[ci][t+4], v);
        acc3[t] += v;
      }
    }
    float mean = 0.f;
    for (int t = 0; t < BINSZ; t++) mean += gelu_f(acc3[t]*sc + sh);
    feat[bin*64 + c] = mean * 0.1f;
  }
}

// ---------------------------------------------------------------- embed + PE
__global__ void embed_kernel(const float* __restrict__ feat, const int* __restrict__ msk,
                             const float* __restrict__ proj_w, const float* __restrict__ proj_b,
                             const float* __restrict__ cls_token, const float* __restrict__ mask_token,
                             float* __restrict__ h) {
  int s_ = blockIdx.x;
  int b  = blockIdx.y;
  int tid = threadIdx.x;
  __shared__ __align__(16) float fs[64];
  float out[4];
  if (s_ == 0) {
#pragma unroll
    for (int u = 0; u < 4; u++) out[u] = cls_token[tid*4+u];
  } else {
    int bin = b*NBINS + (s_-1);
    if (tid < 16) ((float4*)fs)[tid] = ((const float4*)(feat + (size_t)bin*64))[tid];
    __syncthreads();
    int m_ = msk[bin];
#pragma unroll
    for (int u = 0; u < 4; u++) {
      int d = tid*4+u;
      float acc = proj_b[d];
      for (int ci = 0; ci < 64; ci++) acc = fmaf(fs[ci], proj_w[ci*DMODEL + d], acc);
      out[u] = m_ ? mask_token[d] : acc;
    }
  }
  const float c0 = -0.008994473019507992f;  // -ln(10000)/1024
#pragma unroll
  for (int u = 0; u < 4; u++) {
    int d = tid*4+u;
    float div = expf(c0 * (float)(d & ~1));
    float ang = (float)s_ * div;
    float pe = (d & 1) ? cosf(ang) : sinf(ang);
    h[((size_t)(b*SEQ + s_))*DMODEL + d] = out[u] + pe;
  }
}

// ---------------------------------------------------------------- layernorm
__global__ void ln_kernel(const float* __restrict__ x, float* __restrict__ out,
                          const float* __restrict__ g, const float* __restrict__ b) {
  int t = blockIdx.x, tid = threadIdx.x;
  float4 v = ((const float4*)(x + (size_t)t*DMODEL))[tid];
  float s  = v.x+v.y+v.z+v.w;
  float sq = v.x*v.x+v.y*v.y+v.z*v.z+v.w*v.w;
  for (int off = 32; off; off >>= 1) { s += __shfl_down(s, off); sq += __shfl_down(sq, off); }
  __shared__ float ss[4], ssq[4], mv[2];
  int w = tid >> 6, l = tid & 63;
  if (l == 0) { ss[w] = s; ssq[w] = sq; }
  __syncthreads();
  if (tid == 0) {
    float a = 0, c = 0;
    for (int i = 0; i < 4; i++) { a += ss[i]; c += ssq[i]; }
    float mean = a * (1.f/DMODEL);
    float var  = c * (1.f/DMODEL) - mean*mean;
    mv[0] = mean; mv[1] = rsqrtf(var + 1e-5f);
  }
  __syncthreads();
  float mean = mv[0], inv = mv[1];
  float4 gg = ((const float4*)g)[tid];
  float4 bb = ((const float4*)b)[tid];
  float4 o;
  o.x = (v.x-mean)*inv*gg.x + bb.x;
  o.y = (v.y-mean)*inv*gg.y + bb.y;
  o.z = (v.z-mean)*inv*gg.z + bb.z;
  o.w = (v.w-mean)*inv*gg.w + bb.w;
  ((float4*)(out + (size_t)t*DMODEL))[tid] = o;
}

// ---------------------------------------------------------------- bf16 MFMA GEMM, N=1024, K=1024
// MODE 0: C[r] = A[r]@W + bias                    (QKV)
// MODE 1: C[r] += A[r]@W + bias                   (WO residual)
// MODE 2: MoE ffn1: gather A row = token(f>>2), out hid[f] = gelu(...), per-expert bias
// MODE 3: MoE ffn2: gather A row = hid[f], out y[f] = gate[f]*(...), per-expert bias
template<int MODE>
__global__ __launch_bounds__(256) void gemm_bf16(
    const float* __restrict__ A, const float* __restrict__ W,
    const float* __restrict__ bias, float* __restrict__ C, int M,
    const int* __restrict__ rowmap, const int* __restrict__ cnt,
    const float* __restrict__ gate) {
  int tid = threadIdx.x;
  int rowbase, validrows, e = 0;
  const float* Wb = W;
  if (MODE <= 1) {
    rowbase = blockIdx.x * 64;
    validrows = M - rowbase; if (validrows > 64) validrows = 64;
  } else {
    e = blockIdx.x / 18;
    int p0 = (blockIdx.x % 18) * 64;
    int ce = cnt[e];
    if (p0 >= ce) return;
    rowbase = p0;
    validrows = ce - p0; if (validrows > 64) validrows = 64;
    Wb = W + (size_t)e * 1024 * 1024;
  }
  int colbase = blockIdx.y * 64;

  __shared__ __align__(16) __bf16 As[4][64][8];   // [kgroup][row][8k]
  __shared__ __align__(16) __bf16 Ws[4][64][8];   // [kgroup][col][8k]  (transposed W)
  __shared__ int srcrow[64];
  __shared__ int frow[64];

  if (tid < 64) {
    if (MODE <= 1) { srcrow[tid] = rowbase + tid; frow[tid] = rowbase + tid; }
    else if (tid < validrows) {
      int f = rowmap[e*CAPACITY + rowbase + tid];
      frow[tid] = f;
      srcrow[tid] = (MODE == 2) ? (f >> 2) : f;
    } else { frow[tid] = 0; srcrow[tid] = 0; }
  }
  __syncthreads();

  // staging assignments
  int arow = tid >> 2, ag = tid & 3;           // A: row, k-group
  int wcol = tid & 63, wg = tid >> 6;          // W: col, k-group
  const float* Ap = A + (size_t)srcrow[arow] * 1024 + ag * 8;
  const float* Wp = Wb + (size_t)(wg * 8) * 1024 + colbase + wcol;

  // fragment read/compute assignments
  int wv_ = tid >> 6;                 // wave id
  int wr = wv_ >> 1, wc = wv_ & 1;    // wave 32x32 quadrant
  int l  = tid & 63;
  int lr = l & 15, lg = l >> 4;

  f32x4 acc[2][2] = {};

  for (int kt = 0; kt < 1024; kt += 32) {
    // global loads (issue before barrier)
    float4 a_lo = *(const float4*)(Ap + kt);
    float4 a_hi = *(const float4*)(Ap + kt + 4);
    float wreg[8];
#pragma unroll
    for (int j = 0; j < 8; j++) wreg[j] = Wp[(size_t)(kt + j) * 1024];

    __syncthreads();   // previous iteration's compute done
    bf16x8 av;
    av[0] = (__bf16)a_lo.x; av[1] = (__bf16)a_lo.y; av[2] = (__bf16)a_lo.z; av[3] = (__bf16)a_lo.w;
    av[4] = (__bf16)a_hi.x; av[5] = (__bf16)a_hi.y; av[6] = (__bf16)a_hi.z; av[7] = (__bf16)a_hi.w;
    *(bf16x8*)&As[ag][arow][0] = av;
    bf16x8 wvv;
#pragma unroll
    for (int j = 0; j < 8; j++) wvv[j] = (__bf16)wreg[j];
    *(bf16x8*)&Ws[wg][wcol][0] = wvv;
    __syncthreads();

    bf16x8 a0 = *(const bf16x8*)&As[lg][wr*32 + lr][0];
    bf16x8 a1 = *(const bf16x8*)&As[lg][wr*32 + 16 + lr][0];
    bf16x8 b0 = *(const bf16x8*)&Ws[lg][wc*32 + lr][0];
    bf16x8 b1 = *(const bf16x8*)&Ws[lg][wc*32 + 16 + lr][0];
    acc[0][0] = __builtin_amdgcn_mfma_f32_16x16x32_bf16(a0, b0, acc[0][0], 0, 0, 0);
    acc[0][1] = __builtin_amdgcn_mfma_f32_16x16x32_bf16(a0, b1, acc[0][1], 0, 0, 0);
    acc[1][0] = __builtin_amdgcn_mfma_f32_16x16x32_bf16(a1, b0, acc[1][0], 0, 0, 0);
    acc[1][1] = __builtin_amdgcn_mfma_f32_16x16x32_bf16(a1, b1, acc[1][1], 0, 0, 0);
  }

  // epilogue: C/D layout col = l&15, row = (l>>4)*4 + i
  const float* bptr = (MODE >= 2) ? (bias + (size_t)e * 1024) : bias;
#pragma unroll
  for (int fj = 0; fj < 2; fj++) {
    int col = wc*32 + fj*16 + lr;
    float bv = bptr[colbase + col];
#pragma unroll
    for (int fi = 0; fi < 2; fi++) {
#pragma unroll
      for (int i = 0; i < 4; i++) {
        int r = wr*32 + fi*16 + lg*4 + i;
        if (r >= validrows) continue;
        float val = acc[fi][fj][i] + bv;
        if (MODE == 0) {
          C[(size_t)(rowbase + r)*1024 + colbase + col] = val;
        } else if (MODE == 1) {
          float* p = C + (size_t)(rowbase + r)*1024 + colbase + col;
          *p = *p + val;
        } else if (MODE == 2) {
          C[(size_t)frow[r]*1024 + colbase + col] = gelu_f(val);
        } else {
          C[(size_t)frow[r]*1024 + colbase + col] = gate[frow[r]] * val;
        }
      }
    }
  }
}

// ---------------------------------------------------------------- tiled attention (flash-style, fp32)
// block = (q-tile 64 rows, b*h); 256 threads; K/V tiles of 64 staged in LDS.
#define APAD 132
__global__ __launch_bounds__(256) void attn_tiled(const float* __restrict__ q,
                                                  const float* __restrict__ k,
                                                  const float* __restrict__ v,
                                                  float* __restrict__ o) {
  int qt = blockIdx.x;           // 0..8
  int bh = blockIdx.y;           // 0..63
  int b = bh >> 3, hh = bh & 7;
  int tid = threadIdx.x;
  int qt0 = qt * 64;

  __shared__ __align__(16) float Qs[64][APAD];
  __shared__ __align__(16) float Ks[64][APAD];
  __shared__ __align__(16) float Vs[64][APAD];
  __shared__ float S_lds[64][68];
  __shared__ float m_s[64], l_s[64], al_s[64];

  const float scale = 0.08838834764831845f;  // 1/sqrt(128)

  // stage Q tile (row-major, coalesced)
  {
    int r = tid >> 2, dq = tid & 3;
    int tok = qt0 + r; if (tok >= SEQ) tok = SEQ - 1;
    const float* src = q + ((size_t)(b*SEQ + tok))*DMODEL + hh*DHEAD + dq*32;
#pragma unroll
    for (int j = 0; j < 8; j++) *(float4*)&Qs[r][dq*32 + 4*j] = *(const float4*)(src + 4*j);
  }
  if (tid < 64) { m_s[tid] = -1e30f; l_s[tid] = 0.f; }

  int qg = tid >> 4;       // 16 groups of 4 q-rows
  int kg = tid & 15;       // k lane (k = kg + 16j, strided)
  int q0 = qg * 4;
  int d0 = kg * 8;         // PV: same qg rows, 8 d-cols

  float O[4][8] = {};

  for (int ktile = 0; ktile < 9; ktile++) {
    int kt0 = ktile * 64;
    __syncthreads();
    // stage K, V tiles
    {
      int r = tid >> 2, dq = tid & 3;
      int tok = kt0 + r; if (tok >= SEQ) tok = SEQ - 1;
      const float* ksrc = k + ((size_t)(b*SEQ + tok))*DMODEL + hh*DHEAD + dq*32;
      const float* vsrc = v + ((size_t)(b*SEQ + tok))*DMODEL + hh*DHEAD + dq*32;
#pragma unroll
      for (int j = 0; j < 8; j++) {
        *(float4*)&Ks[r][dq*32 + 4*j] = *(const float4*)(ksrc + 4*j);
        *(float4*)&Vs[r][dq*32 + 4*j] = *(const float4*)(vsrc + 4*j);
      }
    }
    __syncthreads();
    // scores: s[i][j] = dot(Q[q0+i], K[kg+16j])
    float s[4][4] = {};
    for (int d = 0; d < DHEAD; d += 4) {
      float4 qv[4], kv[4];
#pragma unroll
      for (int i = 0; i < 4; i++) qv[i] = *(const float4*)&Qs[q0+i][d];
#pragma unroll
      for (int j = 0; j < 4; j++) kv[j] = *(const float4*)&Ks[kg+16*j][d];
#pragma unroll
      for (int i = 0; i < 4; i++)
#pragma unroll
        for (int j = 0; j < 4; j++) {
          s[i][j] = fmaf(qv[i].x, kv[j].x, s[i][j]);
          s[i][j] = fmaf(qv[i].y, kv[j].y, s[i][j]);
          s[i][j] = fmaf(qv[i].z, kv[j].z, s[i][j]);
          s[i][j] = fmaf(qv[i].w, kv[j].w, s[i][j]);
        }
    }
    float mrow[4];
#pragma unroll
    for (int i = 0; i < 4; i++) {
      mrow[i] = -1e30f;
#pragma unroll
      for (int j = 0; j < 4; j++) {
        bool valid = (kt0 + kg + 16*j) < SEQ;
        s[i][j] = valid ? s[i][j]*scale : -1e30f;
        mrow[i] = fmaxf(mrow[i], s[i][j]);
      }
    }
#pragma unroll
    for (int off = 8; off; off >>= 1)
#pragma unroll
      for (int i = 0; i < 4; i++) mrow[i] = fmaxf(mrow[i], __shfl_xor(mrow[i], off, 16));
    float mnew[4], alpha[4], rsum[4];
#pragma unroll
    for (int i = 0; i < 4; i++) {
      float mold = m_s[q0+i];
      mnew[i] = fmaxf(mold, mrow[i]);
      alpha[i] = expf(mold - mnew[i]);
      rsum[i] = 0.f;
#pragma unroll
      for (int j = 0; j < 4; j++) { float p = expf(s[i][j] - mnew[i]); s[i][j] = p; rsum[i] += p; }
    }
#pragma unroll
    for (int off = 8; off; off >>= 1)
#pragma unroll
      for (int i = 0; i < 4; i++) rsum[i] += __shfl_xor(rsum[i], off, 16);
#pragma unroll
    for (int i = 0; i < 4; i++)
#pragma unroll
      for (int j = 0; j < 4; j++) S_lds[q0+i][kg + 16*j] = s[i][j];
    if (kg == 0) {
#pragma unroll
      for (int i = 0; i < 4; i++) {
        m_s[q0+i] = mnew[i];
        al_s[q0+i] = alpha[i];
        l_s[q0+i] = l_s[q0+i]*alpha[i] + rsum[i];
      }
    }
    __syncthreads();
    // PV: O[q0..q0+3][d0..d0+7] += P * V  (after rescale by alpha)
    float av4[4];
#pragma unroll
    for (int i = 0; i < 4; i++) av4[i] = al_s[q0+i];
#pragma unroll
    for (int i = 0; i < 4; i++)
#pragma unroll
      for (int u = 0; u < 8; u++) O[i][u] *= av4[i];
    for (int kk = 0; kk < 64; kk++) {
      float4 v0 = *(const float4*)&Vs[kk][d0];
      float4 v1 = *(const float4*)&Vs[kk][d0+4];
      float p0 = S_lds[q0+0][kk], p1 = S_lds[q0+1][kk];
      float p2 = S_lds[q0+2][kk], p3 = S_lds[q0+3][kk];
      O[0][0] = fmaf(p0, v0.x, O[0][0]); O[0][1] = fmaf(p0, v0.y, O[0][1]);
      O[0][2] = fmaf(p0, v0.z, O[0][2]); O[0][3] = fmaf(p0, v0.w, O[0][3]);
      O[0][4] = fmaf(p0, v1.x, O[0][4]); O[0][5] = fmaf(p0, v1.y, O[0][5]);
      O[0][6] = fmaf(p0, v1.z, O[0][6]); O[0][7] = fmaf(p0, v1.w, O[0][7]);
      O[1][0] = fmaf(p1, v0.x, O[1][0]); O[1][1] = fmaf(p1, v0.y, O[1][1]);
      O[1][2] = fmaf(p1, v0.z, O[1][2]); O[1][3] = fmaf(p1, v0.w, O[1][3]);
      O[1][4] = fmaf(p1, v1.x, O[1][4]); O[1][5] = fmaf(p1, v1.y, O[1][5]);
      O[1][6] = fmaf(p1, v1.z, O[1][6]); O[1][7] = fmaf(p1, v1.w, O[1][7]);
      O[2][0] = fmaf(p2, v0.x, O[2][0]); O[2][1] = fmaf(p2, v0.y, O[2][1]);
      O[2][2] = fmaf(p2, v0.z, O[2][2]); O[2][3] = fmaf(p2, v0.w, O[2][3]);
      O[2][4] = fmaf(p2, v1.x, O[2][4]); O[2][5] = fmaf(p2, v1.y, O[2][5]);
      O[2][6] = fmaf(p2, v1.z, O[2][6]); O[2][7] = fmaf(p2, v1.w, O[2][7]);
      O[3][0] = fmaf(p3, v0.x, O[3][0]); O[3][1] = fmaf(p3, v0.y, O[3][1]);
      O[3][2] = fmaf(p3, v0.z, O[3][2]); O[3][3] = fmaf(p3, v0.w, O[3][3]);
      O[3][4] = fmaf(p3, v1.x, O[3][4]); O[3][5] = fmaf(p3, v1.y, O[3][5]);
      O[3][6] = fmaf(p3, v1.z, O[3][6]); O[3][7] = fmaf(p3, v1.w, O[3][7]);
    }
  }
  __syncthreads();
#pragma unroll
  for (int i = 0; i < 4; i++) {
    int tok = qt0 + q0 + i;
    if (tok < SEQ) {
      float inv = 1.f / l_s[q0+i];
      float* dst = o + ((size_t)(b*SEQ + tok))*DMODEL + hh*DHEAD + d0;
      *(float4*)dst     = make_float4(O[i][0]*inv, O[i][1]*inv, O[i][2]*inv, O[i][3]*inv);
      *(float4*)(dst+4) = make_float4(O[i][4]*inv, O[i][5]*inv, O[i][6]*inv, O[i][7]*inv);
    }
  }
}

// ---------------------------------------------------------------- MoE gating (softmax + top-4)
__global__ void moe_gate(const float* __restrict__ m, const float* __restrict__ wg,
                         const float* __restrict__ bg, int* __restrict__ idx,
                         float* __restrict__ gate) {
  int t = blockIdx.x, tid = threadIdx.x;
  __shared__ __align__(16) float xs[DMODEL];
  __shared__ float probs[32];
  ((float4*)xs)[tid] = ((const float4*)(m + (size_t)t*DMODEL))[tid];
  __syncthreads();
  int e = tid >> 3, sub = tid & 7;
  if (e < NEXP) {
    float p = 0.f;
    for (int d = sub; d < DMODEL; d += 8) p = fmaf(xs[d], wg[d*NEXP + e], p);
    p += __shfl_down(p, 4, 8);
    p += __shfl_down(p, 2, 8);
    p += __shfl_down(p, 1, 8);
    if (sub == 0) probs[e] = p + bg[e];
  }
  __syncthreads();
  if (tid == 0) {
    float mx = probs[0];
    for (int i = 1; i < NEXP; i++) mx = fmaxf(mx, probs[i]);
    float ssum = 0.f;
    for (int i = 0; i < NEXP; i++) { probs[i] = expf(probs[i]-mx); ssum += probs[i]; }
    float invs = 1.f / ssum;
    float gv[TOPK]; int gi[TOPK]; float gsum = 0.f;
    for (int kk = 0; kk < TOPK; kk++) {
      float best = -1.f; int bi = 0;
      for (int i = 0; i < NEXP; i++) if (probs[i] > best) { best = probs[i]; bi = i; }
      gv[kk] = best * invs; gi[kk] = bi; probs[bi] = -1.f; gsum += gv[kk];
    }
    float ginv = 1.f / gsum;
    for (int kk = 0; kk < TOPK; kk++) { idx[t*TOPK+kk] = gi[kk]; gate[t*TOPK+kk] = gv[kk]*ginv; }
  }
}

// ---------------------------------------------------------------- MoE dispatch (capacity scan)
__global__ void moe_dispatch(const int* __restrict__ idx, int* __restrict__ slot,
                             int* __restrict__ rowmap, int* __restrict__ cnt) {
  int e = blockIdx.x, tid = threadIdx.x;
  __shared__ int scan[256];
  int base = 0;
  for (int c0 = 0; c0 < TKF; c0 += 256) {
    int f = c0 + tid;
    int match = (f < TKF && idx[f] == e) ? 1 : 0;
    scan[tid] = match;
    __syncthreads();
    for (int off = 1; off < 256; off <<= 1) {
      int vv = (tid >= off) ? scan[tid-off] : 0;
      __syncthreads();
      scan[tid] += vv;
      __syncthreads();
    }
    int incl = scan[tid];
    int total = scan[255];
    if (match) {
      int pos = base + incl - 1;
      if (pos < CAPACITY) { slot[f] = pos; rowmap[e*CAPACITY + pos] = f; }
      else slot[f] = -1;
    }
    base += total;
    __syncthreads();
  }
  if (tid == 0) cnt[e] = (base < CAPACITY) ? base : CAPACITY;
}

// ---------------------------------------------------------------- MoE combine
__global__ void moe_sum(const float* __restrict__ y, const int* __restrict__ slot,
                        float* __restrict__ h) {
  int t = blockIdx.x, d4 = threadIdx.x;
  float4 acc = ((float4*)(h + (size_t)t*DMODEL))[d4];
#pragma unroll
  for (int kk = 0; kk < TOPK; kk++) {
    int f = t*TOPK + kk;
    if (slot[f] >= 0) {
      float4 yv = ((const float4*)(y + (size_t)f*DMODEL))[d4];
      acc.x += yv.x; acc.y += yv.y; acc.z += yv.z; acc.w += yv.w;
    }
  }
  ((float4*)(h + (size_t)t*DMODEL))[d4] = acc;
}

// ---------------------------------------------------------------- final output
__global__ void final_copy(const float* __restrict__ h, float* __restrict__ out) {
  int b = blockIdx.x, tid = threadIdx.x;
  float4 v = ((const float4*)(h + (size_t)b*SEQ*DMODEL))[tid];
  ((float4*)(out + (size_t)b*DMODEL))[tid] = v;
}

// ---------------------------------------------------------------- host
extern "C" void kernel_launch(void* const* d_in, const int* in_sizes, int n_in,
                              void* d_out, int out_size, void* d_ws, size_t ws_size,
                              hipStream_t stream) {
  (void)in_sizes; (void)n_in; (void)out_size; (void)ws_size;
  const float* x         = (const float*)d_in[0];
  const float* conv_w1   = (const float*)d_in[1];
  const float* conv_w2   = (const float*)d_in[2];
  const float* conv_w3   = (const float*)d_in[3];
  const float* bn1_g     = (const float*)d_in[4];
  const float* bn1_b     = (const float*)d_in[5];
  const float* bn2_g     = (const float*)d_in[6];
  const float* bn2_b     = (const float*)d_in[7];
  const float* bn3_g     = (const float*)d_in[8];
  const float* bn3_b     = (const float*)d_in[9];
  const float* proj_w    = (const float*)d_in[10];
  const float* proj_b    = (const float*)d_in[11];
  const float* cls_token = (const float*)d_in[12];
  const float* mask_tok  = (const float*)d_in[13];
  const float* ln1_g     = (const float*)d_in[14];
  const float* ln1_b     = (const float*)d_in[15];
  const float* ln2_g     = (const float*)d_in[16];
  const float* ln2_b     = (const float*)d_in[17];
  const float* wq        = (const float*)d_in[18];
  const float* wk        = (const float*)d_in[19];
  const float* wv        = (const float*)d_in[20];
  const float* wo        = (const float*)d_in[21];
  const float* bq        = (const float*)d_in[22];
  const float* bk        = (const float*)d_in[23];
  const float* bv        = (const float*)d_in[24];
  const float* bo        = (const float*)d_in[25];
  const float* wg        = (const float*)d_in[26];
  const float* bg        = (const float*)d_in[27];
  const float* we1       = (const float*)d_in[28];
  const float* be1       = (const float*)d_in[29];
  const float* we2       = (const float*)d_in[30];
  const float* be2       = (const float*)d_in[31];
  float* out = (float*)d_out;

  float* ws = (float*)d_ws;
  const size_t TD = (size_t)NTOK * DMODEL;   // 4,202,496 floats
  float* h    = ws;
  float* xbuf = ws + TD;
  float* qb   = ws + 2*TD;
  float* kb   = ws + 3*TD;
  float* vb   = ws + 4*TD;
  float* ao   = ws + 5*TD;
  float* hid  = ws + 2*TD;          // aliases qb..ao (TKF*1024 == 4*TD); used after attn+WO
  float* yb   = ws + 6*TD;          // 4*TD
  float* feat = ws + 10*TD;         // NBINTOT*64
  float* gate = feat + (size_t)NBINTOT*64;
  int* idx    = (int*)(gate + TKF);
  int* slot   = idx + TKF;
  int* rowmap = slot + TKF;
  int* cnt    = rowmap + NEXP*CAPACITY;
  int* msk    = cnt + 32;

  conv_frontend<<<NBINTOT, 64, 0, stream>>>(x, conv_w1, conv_w2, conv_w3,
      bn1_g, bn1_b, bn2_g, bn2_b, bn3_g, bn3_b, feat, msk);
  embed_kernel<<<dim3(SEQ, BATCH), 256, 0, stream>>>(feat, msk, proj_w, proj_b,
      cls_token, mask_tok, h);

  dim3 gdense((NTOK + 63)/64, 16);       // 65 x 16
  dim3 gmoe(NEXP*18, 16);                // 540 x 16

  for (int l = 0; l < NLAYER; l++) {
    const float* wq_l = wq + (size_t)l*DMODEL*DMODEL;
    const float* wk_l = wk + (size_t)l*DMODEL*DMODEL;
    const float* wv_l = wv + (size_t)l*DMODEL*DMODEL;
    const float* wo_l = wo + (size_t)l*DMODEL*DMODEL;
    const float* we1_l = we1 + (size_t)l*NEXP*DMODEL*1024;
    const float* we2_l = we2 + (size_t)l*NEXP*1024*DMODEL;

    ln_kernel<<<NTOK, 256, 0, stream>>>(h, xbuf, ln1_g + (size_t)l*DMODEL, ln1_b + (size_t)l*DMODEL);
    gemm_bf16<0><<<gdense, 256, 0, stream>>>(xbuf, wq_l, bq + (size_t)l*DMODEL, qb, NTOK, nullptr, nullptr, nullptr);
    gemm_bf16<0><<<gdense, 256, 0, stream>>>(xbuf, wk_l, bk + (size_t)l*DMODEL, kb, NTOK, nullptr, nullptr, nullptr);
    gemm_bf16<0><<<gdense, 256, 0, stream>>>(xbuf, wv_l, bv + (size_t)l*DMODEL, vb, NTOK, nullptr, nullptr, nullptr);
    attn_tiled<<<dim3(9, BATCH*NHEAD), 256, 0, stream>>>(qb, kb, vb, ao);
    gemm_bf16<1><<<gdense, 256, 0, stream>>>(ao, wo_l, bo + (size_t)l*DMODEL, h, NTOK, nullptr, nullptr, nullptr);
    ln_kernel<<<NTOK, 256, 0, stream>>>(h, xbuf, ln2_g + (size_t)l*DMODEL, ln2_b + (size_t)l*DMODEL);
    moe_gate<<<NTOK, 256, 0, stream>>>(xbuf, wg + (size_t)l*DMODEL*NEXP, bg + (size_t)l*NEXP, idx, gate);
    moe_dispatch<<<NEXP, 256, 0, stream>>>(idx, slot, rowmap, cnt);
    gemm_bf16<2><<<gmoe, 256, 0, stream>>>(xbuf, we1_l, be1 + (size_t)l*NEXP*1024, hid, 0, rowmap, cnt, nullptr);
    gemm_bf16<3><<<gmoe, 256, 0, stream>>>(hid, we2_l, be2 + (size_t)l*NEXP*1024, yb, 0, rowmap, cnt, gate);
    moe_sum<<<NTOK, 256, 0, stream>>>(yb, slot, h);
  }
  final_copy<<<BATCH, 256, 0, stream>>>(h, out);
}

// Round 3
// 4639.041 us; speedup vs baseline: 2.8406x; 1.1367x over previous
//
#include <hip/hip_runtime.h>
#include <hip/hip_bf16.h>
#include <math.h>

#define BATCH   8
#define NBINS   512
#define BINSZ   10
#define DMODEL  1024
#define NHEAD   8
#define DHEAD   128
#define NLAYER  4
#define NEXP    30
#define TOPK    4
#define SEQ     513            // NBINS + 1
#define NTOK    (BATCH*SEQ)    // 4104
#define NBINTOT (BATCH*NBINS)  // 4096
#define CAPACITY 1152
#define TKF     (NTOK*TOPK)    // 16416

typedef __attribute__((ext_vector_type(8))) __bf16 bf16x8;
typedef __attribute__((ext_vector_type(4))) float f32x4;

__device__ __forceinline__ float gelu_f(float x) {
  return 0.5f * x * (1.0f + erff(x * 0.7071067811865475f));
}

// ---------------------------------------------------------------- conv frontend
// NOTE: every BINSZ loop carries "#pragma unroll" so acc arrays live in VGPRs.
// R2 profile showed 1.29 GB/dispatch scratch traffic from dynamic indexing.
__global__ void conv_frontend(const float* __restrict__ x,
                              const float* __restrict__ w1, const float* __restrict__ w2,
                              const float* __restrict__ w3,
                              const float* __restrict__ g1, const float* __restrict__ b1,
                              const float* __restrict__ g2, const float* __restrict__ b2,
                              const float* __restrict__ g3, const float* __restrict__ b3,
                              float* __restrict__ feat, int* __restrict__ msk) {
  const float bnscale = 0.9999950000374997f;   // 1/sqrt(1+1e-5)
  int bin = blockIdx.x;
  int c = threadIdx.x;
  __shared__ float xs[BINSZ];
  __shared__ float h1[16][BINSZ];
  __shared__ float h2[32][BINSZ];
  if (c < BINSZ) xs[c] = x[bin*BINSZ + c];
  if (c == 0) {
    int all = 1;
#pragma unroll
    for (int t = 0; t < BINSZ; t++) if (x[bin*BINSZ+t] != -100.0f) { all = 0; break; }
    msk[bin] = all;
  }
  __syncthreads();
  if (c < 16) {
    float sc = g1[c]*bnscale, sh = b1[c];
    float wA = w1[c*3], wB = w1[c*3+1], wC = w1[c*3+2];
#pragma unroll
    for (int t = 0; t < BINSZ; t++) {
      float acc = wB * xs[t];
      if (t >= 1) acc = fmaf(wA, xs[t-1], acc);
      if (t <= BINSZ-2) acc = fmaf(wC, xs[t+1], acc);
      h1[c][t] = gelu_f(acc*sc + sh);
    }
  }
  __syncthreads();
  if (c < 32) {
    float sc = g2[c]*bnscale, sh = b2[c];
    float acc2[BINSZ];
#pragma unroll
    for (int t = 0; t < BINSZ; t++) acc2[t] = 0.f;
    for (int ci = 0; ci < 16; ci++) {
      const float* w = w2 + (c*16+ci)*3;
      float wA = w[0], wB = w[1], wC = w[2];
#pragma unroll
      for (int t = 0; t < BINSZ; t++) {
        float v = wB * h1[ci][t];
        if (t >= 2) v = fmaf(wA, h1[ci][t-2], v);
        if (t <= BINSZ-3) v = fmaf(wC, h1[ci][t+2], v);
        acc2[t] += v;
      }
    }
#pragma unroll
    for (int t = 0; t < BINSZ; t++) h2[c][t] = gelu_f(acc2[t]*sc + sh);
  }
  __syncthreads();
  {
    float sc = g3[c]*bnscale, sh = b3[c];
    float acc3[BINSZ];
#pragma unroll
    for (int t = 0; t < BINSZ; t++) acc3[t] = 0.f;
    for (int ci = 0; ci < 32; ci++) {
      const float* w = w3 + (c*32+ci)*3;
      float wA = w[0], wB = w[1], wC = w[2];
#pragma unroll
      for (int t = 0; t < BINSZ; t++) {
        float v = wB * h2[ci][t];
        if (t >= 4) v = fmaf(wA, h2[ci][t-4], v);
        if (t <= BINSZ-5) v = fmaf(wC, h2[ci][t+4], v);
        acc3[t] += v;
      }
    }
    float mean = 0.f;
#pragma unroll
    for (int t = 0; t < BINSZ; t++) mean += gelu_f(acc3[t]*sc + sh);
    feat[bin*64 + c] = mean * 0.1f;
  }
}

// ---------------------------------------------------------------- embed + PE
__global__ void embed_kernel(const float* __restrict__ feat, const int* __restrict__ msk,
                             const float* __restrict__ proj_w, const float* __restrict__ proj_b,
                             const float* __restrict__ cls_token, const float* __restrict__ mask_token,
                             float* __restrict__ h) {
  int s_ = blockIdx.x;
  int b  = blockIdx.y;
  int tid = threadIdx.x;
  __shared__ __align__(16) float fs[64];
  float out[4];
  if (s_ == 0) {
#pragma unroll
    for (int u = 0; u < 4; u++) out[u] = cls_token[tid*4+u];
  } else {
    int bin = b*NBINS + (s_-1);
    if (tid < 16) ((float4*)fs)[tid] = ((const float4*)(feat + (size_t)bin*64))[tid];
    __syncthreads();
    int m_ = msk[bin];
#pragma unroll
    for (int u = 0; u < 4; u++) {
      int d = tid*4+u;
      float acc = proj_b[d];
      for (int ci = 0; ci < 64; ci++) acc = fmaf(fs[ci], proj_w[ci*DMODEL + d], acc);
      out[u] = m_ ? mask_token[d] : acc;
    }
  }
  const float c0 = -0.008994473019507992f;  // -ln(10000)/1024
#pragma unroll
  for (int u = 0; u < 4; u++) {
    int d = tid*4+u;
    float div = expf(c0 * (float)(d & ~1));
    float ang = (float)s_ * div;
    float pe = (d & 1) ? cosf(ang) : sinf(ang);
    h[((size_t)(b*SEQ + s_))*DMODEL + d] = out[u] + pe;
  }
}

// ---------------------------------------------------------------- layernorm
__global__ void ln_kernel(const float* __restrict__ x, float* __restrict__ out,
                          const float* __restrict__ g, const float* __restrict__ b) {
  int t = blockIdx.x, tid = threadIdx.x;
  float4 v = ((const float4*)(x + (size_t)t*DMODEL))[tid];
  float s  = v.x+v.y+v.z+v.w;
  float sq = v.x*v.x+v.y*v.y+v.z*v.z+v.w*v.w;
  for (int off = 32; off; off >>= 1) { s += __shfl_down(s, off); sq += __shfl_down(sq, off); }
  __shared__ float ss[4], ssq[4], mv[2];
  int w = tid >> 6, l = tid & 63;
  if (l == 0) { ss[w] = s; ssq[w] = sq; }
  __syncthreads();
  if (tid == 0) {
    float a = 0, c = 0;
    for (int i = 0; i < 4; i++) { a += ss[i]; c += ssq[i]; }
    float mean = a * (1.f/DMODEL);
    float var  = c * (1.f/DMODEL) - mean*mean;
    mv[0] = mean; mv[1] = rsqrtf(var + 1e-5f);
  }
  __syncthreads();
  float mean = mv[0], inv = mv[1];
  float4 gg = ((const float4*)g)[tid];
  float4 bb = ((const float4*)b)[tid];
  float4 o;
  o.x = (v.x-mean)*inv*gg.x + bb.x;
  o.y = (v.y-mean)*inv*gg.y + bb.y;
  o.z = (v.z-mean)*inv*gg.z + bb.z;
  o.w = (v.w-mean)*inv*gg.w + bb.w;
  ((float4*)(out + (size_t)t*DMODEL))[tid] = o;
}

// ---------------------------------------------------------------- bf16 MFMA GEMM, 128x128 tile
// MODE 0: C[r] = A[r]@W + bias                    (QKV)
// MODE 1: C[r] += A[r]@W + bias                   (WO residual)
// MODE 2: MoE ffn1: gather A row = token(f>>2), out hid[f] = gelu(...), per-expert bias
// MODE 3: MoE ffn2: gather A row = hid[f], out y[f] = gate[f]*(...), per-expert bias
// 512 threads = 8 waves (4 row-quadrants x 2 col-halves), each wave 32x64 out.
// Register-prefetch: next k-step's global loads issue before this step's MFMA.
template<int MODE>
__global__ __launch_bounds__(512) void gemm_bf16(
    const float* __restrict__ A, const float* __restrict__ W,
    const float* __restrict__ bias, float* __restrict__ C, int M,
    const int* __restrict__ rowmap, const int* __restrict__ cnt,
    const float* __restrict__ gate) {
  int tid = threadIdx.x;
  int rowbase, validrows, e = 0;
  const float* Wb = W;
  if (MODE <= 1) {
    rowbase = blockIdx.x * 128;
    validrows = M - rowbase; if (validrows > 128) validrows = 128;
  } else {
    e = blockIdx.x / 9;
    int p0 = (blockIdx.x % 9) * 128;
    int ce = cnt[e];
    if (p0 >= ce) return;
    rowbase = p0;
    validrows = ce - p0; if (validrows > 128) validrows = 128;
    Wb = W + (size_t)e * 1024 * 1024;
  }
  int colbase = blockIdx.y * 128;

  __shared__ __align__(16) __bf16 As[4][128][8];   // [kgroup][row][8k]
  __shared__ __align__(16) __bf16 Bs[4][128][8];   // [kgroup][col][8k]
  __shared__ int srcrow[128];
  __shared__ int frow[128];

  if (tid < 128) {
    if (MODE <= 1) { srcrow[tid] = rowbase + tid; frow[tid] = rowbase + tid; }
    else if (tid < validrows) {
      int f = rowmap[e*CAPACITY + rowbase + tid];
      frow[tid] = f;
      srcrow[tid] = (MODE == 2) ? (f >> 2) : f;
    } else { frow[tid] = 0; srcrow[tid] = 0; }
  }
  __syncthreads();

  // staging assignments
  int arow = tid >> 2, ag = tid & 3;            // A: row, k-group (8 floats each)
  int wcol = tid & 127, wgp = tid >> 7;         // W: col, k-group
  bool aval = (arow < validrows);
  const float* Ap = A + (size_t)srcrow[arow] * 1024 + ag * 8;
  const float* Wp = Wb + (size_t)(wgp * 8) * 1024 + colbase + wcol;

  // compute assignments
  int w  = tid >> 6;
  int wr = w & 3, wc = w >> 2;        // wave quadrant: rows wr*32.., cols wc*64..
  int l  = tid & 63;
  int lr = l & 15, lg = l >> 4;

  f32x4 acc[2][4] = {};

  // prologue loads (kt = 0)
  float4 a_lo = {}, a_hi = {};
  float wreg[8];
  if (aval) { a_lo = *(const float4*)(Ap); a_hi = *(const float4*)(Ap + 4); }
#pragma unroll
  for (int j = 0; j < 8; j++) wreg[j] = Wp[(size_t)j * 1024];

  for (int kt = 0; kt < 1024; kt += 32) {
    __syncthreads();   // previous step's fragment reads done
    bf16x8 av;
    av[0] = (__bf16)a_lo.x; av[1] = (__bf16)a_lo.y; av[2] = (__bf16)a_lo.z; av[3] = (__bf16)a_lo.w;
    av[4] = (__bf16)a_hi.x; av[5] = (__bf16)a_hi.y; av[6] = (__bf16)a_hi.z; av[7] = (__bf16)a_hi.w;
    *(bf16x8*)&As[ag][arow][0] = av;
    bf16x8 bv;
#pragma unroll
    for (int j = 0; j < 8; j++) bv[j] = (__bf16)wreg[j];
    *(bf16x8*)&Bs[wgp][wcol][0] = bv;
    __syncthreads();

    // prefetch next step's globals (hide HBM latency under MFMA)
    if (kt + 32 < 1024) {
      if (aval) {
        a_lo = *(const float4*)(Ap + kt + 32);
        a_hi = *(const float4*)(Ap + kt + 36);
      }
#pragma unroll
      for (int j = 0; j < 8; j++) wreg[j] = Wp[(size_t)(kt + 32 + j) * 1024];
    }

    bf16x8 af[2], bf[4];
    af[0] = *(const bf16x8*)&As[lg][wr*32 + lr][0];
    af[1] = *(const bf16x8*)&As[lg][wr*32 + 16 + lr][0];
#pragma unroll
    for (int fj = 0; fj < 4; fj++) bf[fj] = *(const bf16x8*)&Bs[lg][wc*64 + fj*16 + lr][0];
#pragma unroll
    for (int fi = 0; fi < 2; fi++)
#pragma unroll
      for (int fj = 0; fj < 4; fj++)
        acc[fi][fj] = __builtin_amdgcn_mfma_f32_16x16x32_bf16(af[fi], bf[fj], acc[fi][fj], 0, 0, 0);
  }

  // epilogue: C/D layout col = l&15, row = (l>>4)*4 + i
  const float* bptr = (MODE >= 2) ? (bias + (size_t)e * 1024) : bias;
#pragma unroll
  for (int fj = 0; fj < 4; fj++) {
    int col = wc*64 + fj*16 + lr;
    float bvv = bptr[colbase + col];
#pragma unroll
    for (int fi = 0; fi < 2; fi++) {
#pragma unroll
      for (int i = 0; i < 4; i++) {
        int r = wr*32 + fi*16 + lg*4 + i;
        if (r >= validrows) continue;
        float val = acc[fi][fj][i] + bvv;
        if (MODE == 0) {
          C[(size_t)(rowbase + r)*1024 + colbase + col] = val;
        } else if (MODE == 1) {
          float* p = C + (size_t)(rowbase + r)*1024 + colbase + col;
          *p = *p + val;
        } else if (MODE == 2) {
          C[(size_t)frow[r]*1024 + colbase + col] = gelu_f(val);
        } else {
          C[(size_t)frow[r]*1024 + colbase + col] = gate[frow[r]] * val;
        }
      }
    }
  }
}

// ---------------------------------------------------------------- tiled attention (flash-style, fp32)
#define APAD 132
__global__ __launch_bounds__(256) void attn_tiled(const float* __restrict__ q,
                                                  const float* __restrict__ k,
                                                  const float* __restrict__ v,
                                                  float* __restrict__ o) {
  int qt = blockIdx.x;           // 0..8
  int bh = blockIdx.y;           // 0..63
  int b = bh >> 3, hh = bh & 7;
  int tid = threadIdx.x;
  int qt0 = qt * 64;

  __shared__ __align__(16) float Qs[64][APAD];
  __shared__ __align__(16) float Ks[64][APAD];
  __shared__ __align__(16) float Vs[64][APAD];
  __shared__ float S_lds[64][68];
  __shared__ float m_s[64], l_s[64], al_s[64];

  const float scale = 0.08838834764831845f;  // 1/sqrt(128)

  {
    int r = tid >> 2, dq = tid & 3;
    int tok = qt0 + r; if (tok >= SEQ) tok = SEQ - 1;
    const float* src = q + ((size_t)(b*SEQ + tok))*DMODEL + hh*DHEAD + dq*32;
#pragma unroll
    for (int j = 0; j < 8; j++) *(float4*)&Qs[r][dq*32 + 4*j] = *(const float4*)(src + 4*j);
  }
  if (tid < 64) { m_s[tid] = -1e30f; l_s[tid] = 0.f; }

  int qg = tid >> 4;       // 16 groups of 4 q-rows
  int kg = tid & 15;       // k lane (k = kg + 16j, strided)
  int q0 = qg * 4;
  int d0 = kg * 8;         // PV: same qg rows, 8 d-cols

  float O[4][8] = {};

  for (int ktile = 0; ktile < 9; ktile++) {
    int kt0 = ktile * 64;
    __syncthreads();
    {
      int r = tid >> 2, dq = tid & 3;
      int tok = kt0 + r; if (tok >= SEQ) tok = SEQ - 1;
      const float* ksrc = k + ((size_t)(b*SEQ + tok))*DMODEL + hh*DHEAD + dq*32;
      const float* vsrc = v + ((size_t)(b*SEQ + tok))*DMODEL + hh*DHEAD + dq*32;
#pragma unroll
      for (int j = 0; j < 8; j++) {
        *(float4*)&Ks[r][dq*32 + 4*j] = *(const float4*)(ksrc + 4*j);
        *(float4*)&Vs[r][dq*32 + 4*j] = *(const float4*)(vsrc + 4*j);
      }
    }
    __syncthreads();
    float s[4][4] = {};
    for (int d = 0; d < DHEAD; d += 4) {
      float4 qv[4], kv[4];
#pragma unroll
      for (int i = 0; i < 4; i++) qv[i] = *(const float4*)&Qs[q0+i][d];
#pragma unroll
      for (int j = 0; j < 4; j++) kv[j] = *(const float4*)&Ks[kg+16*j][d];
#pragma unroll
      for (int i = 0; i < 4; i++)
#pragma unroll
        for (int j = 0; j < 4; j++) {
          s[i][j] = fmaf(qv[i].x, kv[j].x, s[i][j]);
          s[i][j] = fmaf(qv[i].y, kv[j].y, s[i][j]);
          s[i][j] = fmaf(qv[i].z, kv[j].z, s[i][j]);
          s[i][j] = fmaf(qv[i].w, kv[j].w, s[i][j]);
        }
    }
    float mrow[4];
#pragma unroll
    for (int i = 0; i < 4; i++) {
      mrow[i] = -1e30f;
#pragma unroll
      for (int j = 0; j < 4; j++) {
        bool valid = (kt0 + kg + 16*j) < SEQ;
        s[i][j] = valid ? s[i][j]*scale : -1e30f;
        mrow[i] = fmaxf(mrow[i], s[i][j]);
      }
    }
#pragma unroll
    for (int off = 8; off; off >>= 1)
#pragma unroll
      for (int i = 0; i < 4; i++) mrow[i] = fmaxf(mrow[i], __shfl_xor(mrow[i], off, 16));
    float mnew[4], alpha[4], rsum[4];
#pragma unroll
    for (int i = 0; i < 4; i++) {
      float mold = m_s[q0+i];
      mnew[i] = fmaxf(mold, mrow[i]);
      alpha[i] = expf(mold - mnew[i]);
      rsum[i] = 0.f;
#pragma unroll
      for (int j = 0; j < 4; j++) { float p = expf(s[i][j] - mnew[i]); s[i][j] = p; rsum[i] += p; }
    }
#pragma unroll
    for (int off = 8; off; off >>= 1)
#pragma unroll
      for (int i = 0; i < 4; i++) rsum[i] += __shfl_xor(rsum[i], off, 16);
#pragma unroll
    for (int i = 0; i < 4; i++)
#pragma unroll
      for (int j = 0; j < 4; j++) S_lds[q0+i][kg + 16*j] = s[i][j];
    if (kg == 0) {
#pragma unroll
      for (int i = 0; i < 4; i++) {
        m_s[q0+i] = mnew[i];
        al_s[q0+i] = alpha[i];
        l_s[q0+i] = l_s[q0+i]*alpha[i] + rsum[i];
      }
    }
    __syncthreads();
    float av4[4];
#pragma unroll
    for (int i = 0; i < 4; i++) av4[i] = al_s[q0+i];
#pragma unroll
    for (int i = 0; i < 4; i++)
#pragma unroll
      for (int u = 0; u < 8; u++) O[i][u] *= av4[i];
    for (int kk = 0; kk < 64; kk++) {
      float4 v0 = *(const float4*)&Vs[kk][d0];
      float4 v1 = *(const float4*)&Vs[kk][d0+4];
      float p0 = S_lds[q0+0][kk], p1 = S_lds[q0+1][kk];
      float p2 = S_lds[q0+2][kk], p3 = S_lds[q0+3][kk];
      O[0][0] = fmaf(p0, v0.x, O[0][0]); O[0][1] = fmaf(p0, v0.y, O[0][1]);
      O[0][2] = fmaf(p0, v0.z, O[0][2]); O[0][3] = fmaf(p0, v0.w, O[0][3]);
      O[0][4] = fmaf(p0, v1.x, O[0][4]); O[0][5] = fmaf(p0, v1.y, O[0][5]);
      O[0][6] = fmaf(p0, v1.z, O[0][6]); O[0][7] = fmaf(p0, v1.w, O[0][7]);
      O[1][0] = fmaf(p1, v0.x, O[1][0]); O[1][1] = fmaf(p1, v0.y, O[1][1]);
      O[1][2] = fmaf(p1, v0.z, O[1][2]); O[1][3] = fmaf(p1, v0.w, O[1][3]);
      O[1][4] = fmaf(p1, v1.x, O[1][4]); O[1][5] = fmaf(p1, v1.y, O[1][5]);
      O[1][6] = fmaf(p1, v1.z, O[1][6]); O[1][7] = fmaf(p1, v1.w, O[1][7]);
      O[2][0] = fmaf(p2, v0.x, O[2][0]); O[2][1] = fmaf(p2, v0.y, O[2][1]);
      O[2][2] = fmaf(p2, v0.z, O[2][2]); O[2][3] = fmaf(p2, v0.w, O[2][3]);
      O[2][4] = fmaf(p2, v1.x, O[2][4]); O[2][5] = fmaf(p2, v1.y, O[2][5]);
      O[2][6] = fmaf(p2, v1.z, O[2][6]); O[2][7] = fmaf(p2, v1.w, O[2][7]);
      O[3][0] = fmaf(p3, v0.x, O[3][0]); O[3][1] = fmaf(p3, v0.y, O[3][1]);
      O[3][2] = fmaf(p3, v0.z, O[3][2]); O[3][3] = fmaf(p3, v0.w, O[3][3]);
      O[3][4] = fmaf(p3, v1.x, O[3][4]); O[3][5] = fmaf(p3, v1.y, O[3][5]);
      O[3][6] = fmaf(p3, v1.z, O[3][6]); O[3][7] = fmaf(p3, v1.w, O[3][7]);
    }
  }
  __syncthreads();
#pragma unroll
  for (int i = 0; i < 4; i++) {
    int tok = qt0 + q0 + i;
    if (tok < SEQ) {
      float inv = 1.f / l_s[q0+i];
      float* dst = o + ((size_t)(b*SEQ + tok))*DMODEL + hh*DHEAD + d0;
      *(float4*)dst     = make_float4(O[i][0]*inv, O[i][1]*inv, O[i][2]*inv, O[i][3]*inv);
      *(float4*)(dst+4) = make_float4(O[i][4]*inv, O[i][5]*inv, O[i][6]*inv, O[i][7]*inv);
    }
  }
}

// ---------------------------------------------------------------- MoE gating (softmax + top-4)
__global__ void moe_gate(const float* __restrict__ m, const float* __restrict__ wg,
                         const float* __restrict__ bg, int* __restrict__ idx,
                         float* __restrict__ gate) {
  int t = blockIdx.x, tid = threadIdx.x;
  __shared__ __align__(16) float xs[DMODEL];
  __shared__ float probs[32];
  ((float4*)xs)[tid] = ((const float4*)(m + (size_t)t*DMODEL))[tid];
  __syncthreads();
  int e = tid >> 3, sub = tid & 7;
  if (e < NEXP) {
    float p = 0.f;
    for (int d = sub; d < DMODEL; d += 8) p = fmaf(xs[d], wg[d*NEXP + e], p);
    p += __shfl_down(p, 4, 8);
    p += __shfl_down(p, 2, 8);
    p += __shfl_down(p, 1, 8);
    if (sub == 0) probs[e] = p + bg[e];
  }
  __syncthreads();
  if (tid == 0) {
    float mx = probs[0];
    for (int i = 1; i < NEXP; i++) mx = fmaxf(mx, probs[i]);
    float ssum = 0.f;
    for (int i = 0; i < NEXP; i++) { probs[i] = expf(probs[i]-mx); ssum += probs[i]; }
    float invs = 1.f / ssum;
    float gv[TOPK]; int gi[TOPK]; float gsum = 0.f;
    for (int kk = 0; kk < TOPK; kk++) {
      float best = -1.f; int bi = 0;
      for (int i = 0; i < NEXP; i++) if (probs[i] > best) { best = probs[i]; bi = i; }
      gv[kk] = best * invs; gi[kk] = bi; probs[bi] = -1.f; gsum += gv[kk];
    }
    float ginv = 1.f / gsum;
    for (int kk = 0; kk < TOPK; kk++) { idx[t*TOPK+kk] = gi[kk]; gate[t*TOPK+kk] = gv[kk]*ginv; }
  }
}

// ---------------------------------------------------------------- MoE dispatch (capacity scan)
__global__ void moe_dispatch(const int* __restrict__ idx, int* __restrict__ slot,
                             int* __restrict__ rowmap, int* __restrict__ cnt) {
  int e = blockIdx.x, tid = threadIdx.x;
  __shared__ int scan[256];
  int base = 0;
  for (int c0 = 0; c0 < TKF; c0 += 256) {
    int f = c0 + tid;
    int match = (f < TKF && idx[f] == e) ? 1 : 0;
    scan[tid] = match;
    __syncthreads();
    for (int off = 1; off < 256; off <<= 1) {
      int vv = (tid >= off) ? scan[tid-off] : 0;
      __syncthreads();
      scan[tid] += vv;
      __syncthreads();
    }
    int incl = scan[tid];
    int total = scan[255];
    if (match) {
      int pos = base + incl - 1;
      if (pos < CAPACITY) { slot[f] = pos; rowmap[e*CAPACITY + pos] = f; }
      else slot[f] = -1;
    }
    base += total;
    __syncthreads();
  }
  if (tid == 0) cnt[e] = (base < CAPACITY) ? base : CAPACITY;
}

// ---------------------------------------------------------------- MoE combine
__global__ void moe_sum(const float* __restrict__ y, const int* __restrict__ slot,
                        float* __restrict__ h) {
  int t = blockIdx.x, d4 = threadIdx.x;
  float4 acc = ((float4*)(h + (size_t)t*DMODEL))[d4];
#pragma unroll
  for (int kk = 0; kk < TOPK; kk++) {
    int f = t*TOPK + kk;
    if (slot[f] >= 0) {
      float4 yv = ((const float4*)(y + (size_t)f*DMODEL))[d4];
      acc.x += yv.x; acc.y += yv.y; acc.z += yv.z; acc.w += yv.w;
    }
  }
  ((float4*)(h + (size_t)t*DMODEL))[d4] = acc;
}

// ---------------------------------------------------------------- final output
__global__ void final_copy(const float* __restrict__ h, float* __restrict__ out) {
  int b = blockIdx.x, tid = threadIdx.x;
  float4 v = ((const float4*)(h + (size_t)b*SEQ*DMODEL))[tid];
  ((float4*)(out + (size_t)b*DMODEL))[tid] = v;
}

// ---------------------------------------------------------------- host
extern "C" void kernel_launch(void* const* d_in, const int* in_sizes, int n_in,
                              void* d_out, int out_size, void* d_ws, size_t ws_size,
                              hipStream_t stream) {
  (void)in_sizes; (void)n_in; (void)out_size; (void)ws_size;
  const float* x         = (const float*)d_in[0];
  const float* conv_w1   = (const float*)d_in[1];
  const float* conv_w2   = (const float*)d_in[2];
  const float* conv_w3   = (const float*)d_in[3];
  const float* bn1_g     = (const float*)d_in[4];
  const float* bn1_b     = (const float*)d_in[5];
  const float* bn2_g     = (const float*)d_in[6];
  const float* bn2_b     = (const float*)d_in[7];
  const float* bn3_g     = (const float*)d_in[8];
  const float* bn3_b     = (const float*)d_in[9];
  const float* proj_w    = (const float*)d_in[10];
  const float* proj_b    = (const float*)d_in[11];
  const float* cls_token = (const float*)d_in[12];
  const float* mask_tok  = (const float*)d_in[13];
  const float* ln1_g     = (const float*)d_in[14];
  const float* ln1_b     = (const float*)d_in[15];
  const float* ln2_g     = (const float*)d_in[16];
  const float* ln2_b     = (const float*)d_in[17];
  const float* wq        = (const float*)d_in[18];
  const float* wk        = (const float*)d_in[19];
  const float* wv        = (const float*)d_in[20];
  const float* wo        = (const float*)d_in[21];
  const float* bq        = (const float*)d_in[22];
  const float* bk        = (const float*)d_in[23];
  const float* bv        = (const float*)d_in[24];
  const float* bo        = (const float*)d_in[25];
  const float* wg        = (const float*)d_in[26];
  const float* bg        = (const float*)d_in[27];
  const float* we1       = (const float*)d_in[28];
  const float* be1       = (const float*)d_in[29];
  const float* we2       = (const float*)d_in[30];
  const float* be2       = (const float*)d_in[31];
  float* out = (float*)d_out;

  float* ws = (float*)d_ws;
  const size_t TD = (size_t)NTOK * DMODEL;   // 4,202,496 floats
  float* h    = ws;
  float* xbuf = ws + TD;
  float* qb   = ws + 2*TD;
  float* kb   = ws + 3*TD;
  float* vb   = ws + 4*TD;
  float* ao   = ws + 5*TD;
  float* hid  = ws + 2*TD;          // aliases qb..ao (TKF*1024 == 4*TD); used after attn+WO
  float* yb   = ws + 6*TD;          // 4*TD
  float* feat = ws + 10*TD;         // NBINTOT*64
  float* gate = feat + (size_t)NBINTOT*64;
  int* idx    = (int*)(gate + TKF);
  int* slot   = idx + TKF;
  int* rowmap = slot + TKF;
  int* cnt    = rowmap + NEXP*CAPACITY;
  int* msk    = cnt + 32;

  conv_frontend<<<NBINTOT, 64, 0, stream>>>(x, conv_w1, conv_w2, conv_w3,
      bn1_g, bn1_b, bn2_g, bn2_b, bn3_g, bn3_b, feat, msk);
  embed_kernel<<<dim3(SEQ, BATCH), 256, 0, stream>>>(feat, msk, proj_w, proj_b,
      cls_token, mask_tok, h);

  dim3 gdense((NTOK + 127)/128, 8);      // 33 x 8
  dim3 gmoe(NEXP*9, 8);                  // 270 x 8

  for (int l = 0; l < NLAYER; l++) {
    const float* wq_l = wq + (size_t)l*DMODEL*DMODEL;
    const float* wk_l = wk + (size_t)l*DMODEL*DMODEL;
    const float* wv_l = wv + (size_t)l*DMODEL*DMODEL;
    const float* wo_l = wo + (size_t)l*DMODEL*DMODEL;
    const float* we1_l = we1 + (size_t)l*NEXP*DMODEL*1024;
    const float* we2_l = we2 + (size_t)l*NEXP*1024*DMODEL;

    ln_kernel<<<NTOK, 256, 0, stream>>>(h, xbuf, ln1_g + (size_t)l*DMODEL, ln1_b + (size_t)l*DMODEL);
    gemm_bf16<0><<<gdense, 512, 0, stream>>>(xbuf, wq_l, bq + (size_t)l*DMODEL, qb, NTOK, nullptr, nullptr, nullptr);
    gemm_bf16<0><<<gdense, 512, 0, stream>>>(xbuf, wk_l, bk + (size_t)l*DMODEL, kb, NTOK, nullptr, nullptr, nullptr);
    gemm_bf16<0><<<gdense, 512, 0, stream>>>(xbuf, wv_l, bv + (size_t)l*DMODEL, vb, NTOK, nullptr, nullptr, nullptr);
    attn_tiled<<<dim3(9, BATCH*NHEAD), 256, 0, stream>>>(qb, kb, vb, ao);
    gemm_bf16<1><<<gdense, 512, 0, stream>>>(ao, wo_l, bo + (size_t)l*DMODEL, h, NTOK, nullptr, nullptr, nullptr);
    ln_kernel<<<NTOK, 256, 0, stream>>>(h, xbuf, ln2_g + (size_t)l*DMODEL, ln2_b + (size_t)l*DMODEL);
    moe_gate<<<NTOK, 256, 0, stream>>>(xbuf, wg + (size_t)l*DMODEL*NEXP, bg + (size_t)l*NEXP, idx, gate);
    moe_dispatch<<<NEXP, 256, 0, stream>>>(idx, slot, rowmap, cnt);
    gemm_bf16<2><<<gmoe, 512, 0, stream>>>(xbuf, we1_l, be1 + (size_t)l*NEXP*1024, hid, 0, rowmap, cnt, nullptr);
    gemm_bf16<3><<<gmoe, 512, 0, stream>>>(hid, we2_l, be2 + (size_t)l*NEXP*1024, yb, 0, rowmap, cnt, gate);
    moe_sum<<<NTOK, 256, 0, stream>>>(yb, slot, h);
  }
  final_copy<<<BATCH, 256, 0, stream>>>(h, out);
}

// Round 5
// 3960.134 us; speedup vs baseline: 3.3276x; 1.1714x over previous
//
#include <hip/hip_runtime.h>
#include <hip/hip_bf16.h>
#include <math.h>

#define BATCH   8
#define NBINS   512
#define BINSZ   10
#define DMODEL  1024
#define NHEAD   8
#define DHEAD   128
#define NLAYER  4
#define NEXP    30
#define TOPK    4
#define SEQ     513            // NBINS + 1
#define NTOK    (BATCH*SEQ)    // 4104
#define NBINTOT (BATCH*NBINS)  // 4096
#define CAPACITY 1152
#define TKF     (NTOK*TOPK)    // 16416

typedef __attribute__((ext_vector_type(8))) __bf16 bf16x8;
typedef __attribute__((ext_vector_type(4))) float f32x4;

__device__ __forceinline__ float gelu_f(float x) {
  return 0.5f * x * (1.0f + erff(x * 0.7071067811865475f));
}

// ---------------------------------------------------------------- conv frontend (v4)
// R3 structure (known correct) with ONE change: acc arrays -> named scalars
// (macro-expanded, guaranteed VGPR; kills the 382 MB scratch write-back that
// was evicting L2 and turning 31 KB of weights into 1.29 GB of HBM fetch).
// fp math order is bit-identical to R3.

#define CSTEP(acc, T, DIL, hr, wA, wB, wC) { \
  float vv_ = (wB) * (hr)[T]; \
  if ((T) >= (DIL)) vv_ = fmaf((wA), (hr)[(T)-(DIL)], vv_); \
  if ((T) + (DIL) <= 9) vv_ = fmaf((wC), (hr)[(T)+(DIL)], vv_); \
  acc += vv_; }

#define CALL10(DIL, hr, wA, wB, wC) \
  CSTEP(t0,0,DIL,hr,wA,wB,wC); CSTEP(t1,1,DIL,hr,wA,wB,wC); \
  CSTEP(t2,2,DIL,hr,wA,wB,wC); CSTEP(t3,3,DIL,hr,wA,wB,wC); \
  CSTEP(t4,4,DIL,hr,wA,wB,wC); CSTEP(t5,5,DIL,hr,wA,wB,wC); \
  CSTEP(t6,6,DIL,hr,wA,wB,wC); CSTEP(t7,7,DIL,hr,wA,wB,wC); \
  CSTEP(t8,8,DIL,hr,wA,wB,wC); CSTEP(t9,9,DIL,hr,wA,wB,wC);

#define ZERO10 float t0=0.f,t1=0.f,t2=0.f,t3=0.f,t4=0.f,t5=0.f,t6=0.f,t7=0.f,t8=0.f,t9=0.f;

#define STORE10(dst, sc, sh) \
  (dst)[0]=gelu_f(t0*(sc)+(sh)); (dst)[1]=gelu_f(t1*(sc)+(sh)); \
  (dst)[2]=gelu_f(t2*(sc)+(sh)); (dst)[3]=gelu_f(t3*(sc)+(sh)); \
  (dst)[4]=gelu_f(t4*(sc)+(sh)); (dst)[5]=gelu_f(t5*(sc)+(sh)); \
  (dst)[6]=gelu_f(t6*(sc)+(sh)); (dst)[7]=gelu_f(t7*(sc)+(sh)); \
  (dst)[8]=gelu_f(t8*(sc)+(sh)); (dst)[9]=gelu_f(t9*(sc)+(sh));

__global__ __launch_bounds__(64) void conv_frontend(const float* __restrict__ x,
                              const float* __restrict__ w1, const float* __restrict__ w2,
                              const float* __restrict__ w3,
                              const float* __restrict__ g1, const float* __restrict__ b1,
                              const float* __restrict__ g2, const float* __restrict__ b2,
                              const float* __restrict__ g3, const float* __restrict__ b3,
                              float* __restrict__ feat, int* __restrict__ msk) {
  const float bnscale = 0.9999950000374997f;   // 1/sqrt(1+1e-5)
  int bin = blockIdx.x;
  int c = threadIdx.x;
  __shared__ float xs[BINSZ];
  __shared__ float h1[16][BINSZ];
  __shared__ float h2[32][BINSZ];
  if (c < BINSZ) xs[c] = x[bin*BINSZ + c];
  if (c == 0) {
    int all = 1;
    for (int t = 0; t < BINSZ; t++) if (x[bin*BINSZ+t] != -100.0f) { all = 0; break; }
    msk[bin] = all;
  }
  __syncthreads();
  if (c < 16) {
    float sc = g1[c]*bnscale, sh = b1[c];
    float wA = w1[c*3], wB = w1[c*3+1], wC = w1[c*3+2];
    const float* hr = &xs[0];
    ZERO10;
    CALL10(1, hr, wA, wB, wC);
    STORE10(&h1[c][0], sc, sh);
  }
  __syncthreads();
  if (c < 32) {
    float sc = g2[c]*bnscale, sh = b2[c];
    ZERO10;
    for (int ci = 0; ci < 16; ci++) {
      const float* w = w2 + (c*16+ci)*3;
      float wA = w[0], wB = w[1], wC = w[2];
      const float* hr = &h1[ci][0];
      CALL10(2, hr, wA, wB, wC);
    }
    STORE10(&h2[c][0], sc, sh);
  }
  __syncthreads();
  {
    float sc = g3[c]*bnscale, sh = b3[c];
    ZERO10;
    for (int ci = 0; ci < 32; ci++) {
      const float* w = w3 + (c*32+ci)*3;
      float wA = w[0], wB = w[1], wC = w[2];
      const float* hr = &h2[ci][0];
      CALL10(4, hr, wA, wB, wC);
    }
    float mean = gelu_f(t0*sc+sh) + gelu_f(t1*sc+sh) + gelu_f(t2*sc+sh)
               + gelu_f(t3*sc+sh) + gelu_f(t4*sc+sh) + gelu_f(t5*sc+sh)
               + gelu_f(t6*sc+sh) + gelu_f(t7*sc+sh) + gelu_f(t8*sc+sh)
               + gelu_f(t9*sc+sh);
    feat[bin*64 + c] = mean * 0.1f;
  }
}

// ---------------------------------------------------------------- embed + PE
__global__ void embed_kernel(const float* __restrict__ feat, const int* __restrict__ msk,
                             const float* __restrict__ proj_w, const float* __restrict__ proj_b,
                             const float* __restrict__ cls_token, const float* __restrict__ mask_token,
                             float* __restrict__ h) {
  int s_ = blockIdx.x;
  int b  = blockIdx.y;
  int tid = threadIdx.x;
  __shared__ __align__(16) float fs[64];
  float out[4];
  if (s_ == 0) {
#pragma unroll
    for (int u = 0; u < 4; u++) out[u] = cls_token[tid*4+u];
  } else {
    int bin = b*NBINS + (s_-1);
    if (tid < 16) ((float4*)fs)[tid] = ((const float4*)(feat + (size_t)bin*64))[tid];
    __syncthreads();
    int m_ = msk[bin];
#pragma unroll
    for (int u = 0; u < 4; u++) {
      int d = tid*4+u;
      float acc = proj_b[d];
      for (int ci = 0; ci < 64; ci++) acc = fmaf(fs[ci], proj_w[ci*DMODEL + d], acc);
      out[u] = m_ ? mask_token[d] : acc;
    }
  }
  const float c0 = -0.008994473019507992f;  // -ln(10000)/1024
#pragma unroll
  for (int u = 0; u < 4; u++) {
    int d = tid*4+u;
    float div = expf(c0 * (float)(d & ~1));
    float ang = (float)s_ * div;
    float pe = (d & 1) ? cosf(ang) : sinf(ang);
    h[((size_t)(b*SEQ + s_))*DMODEL + d] = out[u] + pe;
  }
}

// ---------------------------------------------------------------- layernorm
__global__ void ln_kernel(const float* __restrict__ x, float* __restrict__ out,
                          const float* __restrict__ g, const float* __restrict__ b) {
  int t = blockIdx.x, tid = threadIdx.x;
  float4 v = ((const float4*)(x + (size_t)t*DMODEL))[tid];
  float s  = v.x+v.y+v.z+v.w;
  float sq = v.x*v.x+v.y*v.y+v.z*v.z+v.w*v.w;
  for (int off = 32; off; off >>= 1) { s += __shfl_down(s, off); sq += __shfl_down(sq, off); }
  __shared__ float ss[4], ssq[4], mv[2];
  int w = tid >> 6, l = tid & 63;
  if (l == 0) { ss[w] = s; ssq[w] = sq; }
  __syncthreads();
  if (tid == 0) {
    float a = 0, c = 0;
    for (int i = 0; i < 4; i++) { a += ss[i]; c += ssq[i]; }
    float mean = a * (1.f/DMODEL);
    float var  = c * (1.f/DMODEL) - mean*mean;
    mv[0] = mean; mv[1] = rsqrtf(var + 1e-5f);
  }
  __syncthreads();
  float mean = mv[0], inv = mv[1];
  float4 gg = ((const float4*)g)[tid];
  float4 bb = ((const float4*)b)[tid];
  float4 o;
  o.x = (v.x-mean)*inv*gg.x + bb.x;
  o.y = (v.y-mean)*inv*gg.y + bb.y;
  o.z = (v.z-mean)*inv*gg.z + bb.z;
  o.w = (v.w-mean)*inv*gg.w + bb.w;
  ((float4*)(out + (size_t)t*DMODEL))[tid] = o;
}

// ---------------------------------------------------------------- bf16 MFMA GEMM, 128x128 tile
template<int MODE>
__global__ __launch_bounds__(512) void gemm_bf16(
    const float* __restrict__ A, const float* __restrict__ W,
    const float* __restrict__ bias, float* __restrict__ C, int M,
    const int* __restrict__ rowmap, const int* __restrict__ cnt,
    const float* __restrict__ gate) {
  int tid = threadIdx.x;
  int rowbase, validrows, e = 0;
  const float* Wb = W;
  if (MODE <= 1) {
    rowbase = blockIdx.x * 128;
    validrows = M - rowbase; if (validrows > 128) validrows = 128;
  } else {
    e = blockIdx.x / 9;
    int p0 = (blockIdx.x % 9) * 128;
    int ce = cnt[e];
    if (p0 >= ce) return;
    rowbase = p0;
    validrows = ce - p0; if (validrows > 128) validrows = 128;
    Wb = W + (size_t)e * 1024 * 1024;
  }
  int colbase = blockIdx.y * 128;

  __shared__ __align__(16) __bf16 As[4][128][8];   // [kgroup][row][8k]
  __shared__ __align__(16) __bf16 Bs[4][128][8];   // [kgroup][col][8k]
  __shared__ int srcrow[128];
  __shared__ int frow[128];

  if (tid < 128) {
    if (MODE <= 1) { srcrow[tid] = rowbase + tid; frow[tid] = rowbase + tid; }
    else if (tid < validrows) {
      int f = rowmap[e*CAPACITY + rowbase + tid];
      frow[tid] = f;
      srcrow[tid] = (MODE == 2) ? (f >> 2) : f;
    } else { frow[tid] = 0; srcrow[tid] = 0; }
  }
  __syncthreads();

  // staging assignments
  int arow = tid >> 2, ag = tid & 3;            // A: row, k-group (8 floats each)
  int wcol = tid & 127, wgp = tid >> 7;         // W: col, k-group
  bool aval = (arow < validrows);
  const float* Ap = A + (size_t)srcrow[arow] * 1024 + ag * 8;
  const float* Wp = Wb + (size_t)(wgp * 8) * 1024 + colbase + wcol;

  // compute assignments
  int w  = tid >> 6;
  int wr = w & 3, wc = w >> 2;        // wave quadrant: rows wr*32.., cols wc*64..
  int l  = tid & 63;
  int lr = l & 15, lg = l >> 4;

  f32x4 acc[2][4] = {};

  // prologue loads (kt = 0)
  float4 a_lo = {}, a_hi = {};
  float wreg[8];
  if (aval) { a_lo = *(const float4*)(Ap); a_hi = *(const float4*)(Ap + 4); }
#pragma unroll
  for (int j = 0; j < 8; j++) wreg[j] = Wp[(size_t)j * 1024];

  for (int kt = 0; kt < 1024; kt += 32) {
    __syncthreads();   // previous step's fragment reads done
    bf16x8 av;
    av[0] = (__bf16)a_lo.x; av[1] = (__bf16)a_lo.y; av[2] = (__bf16)a_lo.z; av[3] = (__bf16)a_lo.w;
    av[4] = (__bf16)a_hi.x; av[5] = (__bf16)a_hi.y; av[6] = (__bf16)a_hi.z; av[7] = (__bf16)a_hi.w;
    *(bf16x8*)&As[ag][arow][0] = av;
    bf16x8 bv;
#pragma unroll
    for (int j = 0; j < 8; j++) bv[j] = (__bf16)wreg[j];
    *(bf16x8*)&Bs[wgp][wcol][0] = bv;
    __syncthreads();

    // prefetch next step's globals (hide HBM latency under MFMA)
    if (kt + 32 < 1024) {
      if (aval) {
        a_lo = *(const float4*)(Ap + kt + 32);
        a_hi = *(const float4*)(Ap + kt + 36);
      }
#pragma unroll
      for (int j = 0; j < 8; j++) wreg[j] = Wp[(size_t)(kt + 32 + j) * 1024];
    }

    bf16x8 af[2], bf[4];
    af[0] = *(const bf16x8*)&As[lg][wr*32 + lr][0];
    af[1] = *(const bf16x8*)&As[lg][wr*32 + 16 + lr][0];
#pragma unroll
    for (int fj = 0; fj < 4; fj++) bf[fj] = *(const bf16x8*)&Bs[lg][wc*64 + fj*16 + lr][0];
#pragma unroll
    for (int fi = 0; fi < 2; fi++)
#pragma unroll
      for (int fj = 0; fj < 4; fj++)
        acc[fi][fj] = __builtin_amdgcn_mfma_f32_16x16x32_bf16(af[fi], bf[fj], acc[fi][fj], 0, 0, 0);
  }

  // epilogue: C/D layout col = l&15, row = (l>>4)*4 + i
  const float* bptr = (MODE >= 2) ? (bias + (size_t)e * 1024) : bias;
#pragma unroll
  for (int fj = 0; fj < 4; fj++) {
    int col = wc*64 + fj*16 + lr;
    float bvv = bptr[colbase + col];
#pragma unroll
    for (int fi = 0; fi < 2; fi++) {
#pragma unroll
      for (int i = 0; i < 4; i++) {
        int r = wr*32 + fi*16 + lg*4 + i;
        if (r >= validrows) continue;
        float val = acc[fi][fj][i] + bvv;
        if (MODE == 0) {
          C[(size_t)(rowbase + r)*1024 + colbase + col] = val;
        } else if (MODE == 1) {
          float* p = C + (size_t)(rowbase + r)*1024 + colbase + col;
          *p = *p + val;
        } else if (MODE == 2) {
          C[(size_t)frow[r]*1024 + colbase + col] = gelu_f(val);
        } else {
          C[(size_t)frow[r]*1024 + colbase + col] = gate[frow[r]] * val;
        }
      }
    }
  }
}

// ---------------------------------------------------------------- tiled attention (flash-style, fp32)
#define APAD 132
__global__ __launch_bounds__(256) void attn_tiled(const float* __restrict__ q,
                                                  const float* __restrict__ k,
                                                  const float* __restrict__ v,
                                                  float* __restrict__ o) {
  int qt = blockIdx.x;           // 0..8
  int bh = blockIdx.y;           // 0..63
  int b = bh >> 3, hh = bh & 7;
  int tid = threadIdx.x;
  int qt0 = qt * 64;

  __shared__ __align__(16) float Qs[64][APAD];
  __shared__ __align__(16) float Ks[64][APAD];
  __shared__ __align__(16) float Vs[64][APAD];
  __shared__ float S_lds[64][68];
  __shared__ float m_s[64], l_s[64], al_s[64];

  const float scale = 0.08838834764831845f;  // 1/sqrt(128)

  {
    int r = tid >> 2, dq = tid & 3;
    int tok = qt0 + r; if (tok >= SEQ) tok = SEQ - 1;
    const float* src = q + ((size_t)(b*SEQ + tok))*DMODEL + hh*DHEAD + dq*32;
#pragma unroll
    for (int j = 0; j < 8; j++) *(float4*)&Qs[r][dq*32 + 4*j] = *(const float4*)(src + 4*j);
  }
  if (tid < 64) { m_s[tid] = -1e30f; l_s[tid] = 0.f; }

  int qg = tid >> 4;       // 16 groups of 4 q-rows
  int kg = tid & 15;       // k lane (k = kg + 16j, strided)
  int q0 = qg * 4;
  int d0 = kg * 8;         // PV: same qg rows, 8 d-cols

  float O[4][8] = {};

  for (int ktile = 0; ktile < 9; ktile++) {
    int kt0 = ktile * 64;
    __syncthreads();
    {
      int r = tid >> 2, dq = tid & 3;
      int tok = kt0 + r; if (tok >= SEQ) tok = SEQ - 1;
      const float* ksrc = k + ((size_t)(b*SEQ + tok))*DMODEL + hh*DHEAD + dq*32;
      const float* vsrc = v + ((size_t)(b*SEQ + tok))*DMODEL + hh*DHEAD + dq*32;
#pragma unroll
      for (int j = 0; j < 8; j++) {
        *(float4*)&Ks[r][dq*32 + 4*j] = *(const float4*)(ksrc + 4*j);
        *(float4*)&Vs[r][dq*32 + 4*j] = *(const float4*)(vsrc + 4*j);
      }
    }
    __syncthreads();
    float s[4][4] = {};
    for (int d = 0; d < DHEAD; d += 4) {
      float4 qv[4], kv[4];
#pragma unroll
      for (int i = 0; i < 4; i++) qv[i] = *(const float4*)&Qs[q0+i][d];
#pragma unroll
      for (int j = 0; j < 4; j++) kv[j] = *(const float4*)&Ks[kg+16*j][d];
#pragma unroll
      for (int i = 0; i < 4; i++)
#pragma unroll
        for (int j = 0; j < 4; j++) {
          s[i][j] = fmaf(qv[i].x, kv[j].x, s[i][j]);
          s[i][j] = fmaf(qv[i].y, kv[j].y, s[i][j]);
          s[i][j] = fmaf(qv[i].z, kv[j].z, s[i][j]);
          s[i][j] = fmaf(qv[i].w, kv[j].w, s[i][j]);
        }
    }
    float mrow[4];
#pragma unroll
    for (int i = 0; i < 4; i++) {
      mrow[i] = -1e30f;
#pragma unroll
      for (int j = 0; j < 4; j++) {
        bool valid = (kt0 + kg + 16*j) < SEQ;
        s[i][j] = valid ? s[i][j]*scale : -1e30f;
        mrow[i] = fmaxf(mrow[i], s[i][j]);
      }
    }
#pragma unroll
    for (int off = 8; off; off >>= 1)
#pragma unroll
      for (int i = 0; i < 4; i++) mrow[i] = fmaxf(mrow[i], __shfl_xor(mrow[i], off, 16));
    float mnew[4], alpha[4], rsum[4];
#pragma unroll
    for (int i = 0; i < 4; i++) {
      float mold = m_s[q0+i];
      mnew[i] = fmaxf(mold, mrow[i]);
      alpha[i] = expf(mold - mnew[i]);
      rsum[i] = 0.f;
#pragma unroll
      for (int j = 0; j < 4; j++) { float p = expf(s[i][j] - mnew[i]); s[i][j] = p; rsum[i] += p; }
    }
#pragma unroll
    for (int off = 8; off; off >>= 1)
#pragma unroll
      for (int i = 0; i < 4; i++) rsum[i] += __shfl_xor(rsum[i], off, 16);
#pragma unroll
    for (int i = 0; i < 4; i++)
#pragma unroll
      for (int j = 0; j < 4; j++) S_lds[q0+i][kg + 16*j] = s[i][j];
    if (kg == 0) {
#pragma unroll
      for (int i = 0; i < 4; i++) {
        m_s[q0+i] = mnew[i];
        al_s[q0+i] = alpha[i];
        l_s[q0+i] = l_s[q0+i]*alpha[i] + rsum[i];
      }
    }
    __syncthreads();
    float av4[4];
#pragma unroll
    for (int i = 0; i < 4; i++) av4[i] = al_s[q0+i];
#pragma unroll
    for (int i = 0; i < 4; i++)
#pragma unroll
      for (int u = 0; u < 8; u++) O[i][u] *= av4[i];
    for (int kk = 0; kk < 64; kk++) {
      float4 v0 = *(const float4*)&Vs[kk][d0];
      float4 v1 = *(const float4*)&Vs[kk][d0+4];
      float p0 = S_lds[q0+0][kk], p1 = S_lds[q0+1][kk];
      float p2 = S_lds[q0+2][kk], p3 = S_lds[q0+3][kk];
      O[0][0] = fmaf(p0, v0.x, O[0][0]); O[0][1] = fmaf(p0, v0.y, O[0][1]);
      O[0][2] = fmaf(p0, v0.z, O[0][2]); O[0][3] = fmaf(p0, v0.w, O[0][3]);
      O[0][4] = fmaf(p0, v1.x, O[0][4]); O[0][5] = fmaf(p0, v1.y, O[0][5]);
      O[0][6] = fmaf(p0, v1.z, O[0][6]); O[0][7] = fmaf(p0, v1.w, O[0][7]);
      O[1][0] = fmaf(p1, v0.x, O[1][0]); O[1][1] = fmaf(p1, v0.y, O[1][1]);
      O[1][2] = fmaf(p1, v0.z, O[1][2]); O[1][3] = fmaf(p1, v0.w, O[1][3]);
      O[1][4] = fmaf(p1, v1.x, O[1][4]); O[1][5] = fmaf(p1, v1.y, O[1][5]);
      O[1][6] = fmaf(p1, v1.z, O[1][6]); O[1][7] = fmaf(p1, v1.w, O[1][7]);
      O[2][0] = fmaf(p2, v0.x, O[2][0]); O[2][1] = fmaf(p2, v0.y, O[2][1]);
      O[2][2] = fmaf(p2, v0.z, O[2][2]); O[2][3] = fmaf(p2, v0.w, O[2][3]);
      O[2][4] = fmaf(p2, v1.x, O[2][4]); O[2][5] = fmaf(p2, v1.y, O[2][5]);
      O[2][6] = fmaf(p2, v1.z, O[2][6]); O[2][7] = fmaf(p2, v1.w, O[2][7]);
      O[3][0] = fmaf(p3, v0.x, O[3][0]); O[3][1] = fmaf(p3, v0.y, O[3][1]);
      O[3][2] = fmaf(p3, v0.z, O[3][2]); O[3][3] = fmaf(p3, v0.w, O[3][3]);
      O[3][4] = fmaf(p3, v1.x, O[3][4]); O[3][5] = fmaf(p3, v1.y, O[3][5]);
      O[3][6] = fmaf(p3, v1.z, O[3][6]); O[3][7] = fmaf(p3, v1.w, O[3][7]);
    }
  }
  __syncthreads();
#pragma unroll
  for (int i = 0; i < 4; i++) {
    int tok = qt0 + q0 + i;
    if (tok < SEQ) {
      float inv = 1.f / l_s[q0+i];
      float* dst = o + ((size_t)(b*SEQ + tok))*DMODEL + hh*DHEAD + d0;
      *(float4*)dst     = make_float4(O[i][0]*inv, O[i][1]*inv, O[i][2]*inv, O[i][3]*inv);
      *(float4*)(dst+4) = make_float4(O[i][4]*inv, O[i][5]*inv, O[i][6]*inv, O[i][7]*inv);
    }
  }
}

// ---------------------------------------------------------------- MoE gating (softmax + top-4)
__global__ void moe_gate(const float* __restrict__ m, const float* __restrict__ wg,
                         const float* __restrict__ bg, int* __restrict__ idx,
                         float* __restrict__ gate) {
  int t = blockIdx.x, tid = threadIdx.x;
  __shared__ __align__(16) float xs[DMODEL];
  __shared__ float probs[32];
  ((float4*)xs)[tid] = ((const float4*)(m + (size_t)t*DMODEL))[tid];
  __syncthreads();
  int e = tid >> 3, sub = tid & 7;
  if (e < NEXP) {
    float p = 0.f;
    for (int d = sub; d < DMODEL; d += 8) p = fmaf(xs[d], wg[d*NEXP + e], p);
    p += __shfl_down(p, 4, 8);
    p += __shfl_down(p, 2, 8);
    p += __shfl_down(p, 1, 8);
    if (sub == 0) probs[e] = p + bg[e];
  }
  __syncthreads();
  if (tid == 0) {
    float mx = probs[0];
    for (int i = 1; i < NEXP; i++) mx = fmaxf(mx, probs[i]);
    float ssum = 0.f;
    for (int i = 0; i < NEXP; i++) { probs[i] = expf(probs[i]-mx); ssum += probs[i]; }
    float invs = 1.f / ssum;
    float gv[TOPK]; int gi[TOPK]; float gsum = 0.f;
    for (int kk = 0; kk < TOPK; kk++) {
      float best = -1.f; int bi = 0;
      for (int i = 0; i < NEXP; i++) if (probs[i] > best) { best = probs[i]; bi = i; }
      gv[kk] = best * invs; gi[kk] = bi; probs[bi] = -1.f; gsum += gv[kk];
    }
    float ginv = 1.f / gsum;
    for (int kk = 0; kk < TOPK; kk++) { idx[t*TOPK+kk] = gi[kk]; gate[t*TOPK+kk] = gv[kk]*ginv; }
  }
}

// ---------------------------------------------------------------- MoE dispatch (capacity scan, ballot version)
// one block per expert; sequential 256-chunks; within chunk: wave ballots +
// cross-wave LDS sums. pos = base + matches-in-earlier-waves + matches-in-earlier-lanes.
// Exactly reproduces the reference's flat cumsum ordering.
__global__ void moe_dispatch(const int* __restrict__ idx, int* __restrict__ slot,
                             int* __restrict__ rowmap, int* __restrict__ cnt) {
  int e = blockIdx.x, tid = threadIdx.x;
  int lane = tid & 63, wid = tid >> 6;
  __shared__ int wsum[4];
  int base = 0;
  for (int c0 = 0; c0 < TKF; c0 += 256) {
    int f = c0 + tid;
    int match = (f < TKF && idx[f] == e) ? 1 : 0;
    unsigned long long bal = __ballot(match);
    if (lane == 0) wsum[wid] = __popcll(bal);
    __syncthreads();
    int prefix = 0;
#pragma unroll
    for (int w2 = 0; w2 < 4; w2++) if (w2 < wid) prefix += wsum[w2];
    int total = wsum[0] + wsum[1] + wsum[2] + wsum[3];
    if (match) {
      int pos = base + prefix + __popcll(bal & ((1ull << lane) - 1ull));
      if (pos < CAPACITY) { slot[f] = pos; rowmap[e*CAPACITY + pos] = f; }
      else slot[f] = -1;
    }
    base += total;
    __syncthreads();
  }
  if (tid == 0) cnt[e] = (base < CAPACITY) ? base : CAPACITY;
}

// ---------------------------------------------------------------- MoE combine
__global__ void moe_sum(const float* __restrict__ y, const int* __restrict__ slot,
                        float* __restrict__ h) {
  int t = blockIdx.x, d4 = threadIdx.x;
  float4 acc = ((float4*)(h + (size_t)t*DMODEL))[d4];
#pragma unroll
  for (int kk = 0; kk < TOPK; kk++) {
    int f = t*TOPK + kk;
    if (slot[f] >= 0) {
      float4 yv = ((const float4*)(y + (size_t)f*DMODEL))[d4];
      acc.x += yv.x; acc.y += yv.y; acc.z += yv.z; acc.w += yv.w;
    }
  }
  ((float4*)(h + (size_t)t*DMODEL))[d4] = acc;
}

// ---------------------------------------------------------------- final output
__global__ void final_copy(const float* __restrict__ h, float* __restrict__ out) {
  int b = blockIdx.x, tid = threadIdx.x;
  float4 v = ((const float4*)(h + (size_t)b*SEQ*DMODEL))[tid];
  ((float4*)(out + (size_t)b*DMODEL))[tid] = v;
}

// ---------------------------------------------------------------- host
extern "C" void kernel_launch(void* const* d_in, const int* in_sizes, int n_in,
                              void* d_out, int out_size, void* d_ws, size_t ws_size,
                              hipStream_t stream) {
  (void)in_sizes; (void)n_in; (void)out_size; (void)ws_size;
  const float* x         = (const float*)d_in[0];
  const float* conv_w1   = (const float*)d_in[1];
  const float* conv_w2   = (const float*)d_in[2];
  const float* conv_w3   = (const float*)d_in[3];
  const float* bn1_g     = (const float*)d_in[4];
  const float* bn1_b     = (const float*)d_in[5];
  const float* bn2_g     = (const float*)d_in[6];
  const float* bn2_b     = (const float*)d_in[7];
  const float* bn3_g     = (const float*)d_in[8];
  const float* bn3_b     = (const float*)d_in[9];
  const float* proj_w    = (const float*)d_in[10];
  const float* proj_b    = (const float*)d_in[11];
  const float* cls_token = (const float*)d_in[12];
  const float* mask_tok  = (const float*)d_in[13];
  const float* ln1_g     = (const float*)d_in[14];
  const float* ln1_b     = (const float*)d_in[15];
  const float* ln2_g     = (const float*)d_in[16];
  const float* ln2_b     = (const float*)d_in[17];
  const float* wq        = (const float*)d_in[18];
  const float* wk        = (const float*)d_in[19];
  const float* wv        = (const float*)d_in[20];
  const float* wo        = (const float*)d_in[21];
  const float* bq        = (const float*)d_in[22];
  const float* bk        = (const float*)d_in[23];
  const float* bv        = (const float*)d_in[24];
  const float* bo        = (const float*)d_in[25];
  const float* wg        = (const float*)d_in[26];
  const float* bg        = (const float*)d_in[27];
  const float* we1       = (const float*)d_in[28];
  const float* be1       = (const float*)d_in[29];
  const float* we2       = (const float*)d_in[30];
  const float* be2       = (const float*)d_in[31];
  float* out = (float*)d_out;

  float* ws = (float*)d_ws;
  const size_t TD = (size_t)NTOK * DMODEL;   // 4,202,496 floats
  float* h    = ws;
  float* xbuf = ws + TD;
  float* qb   = ws + 2*TD;
  float* kb   = ws + 3*TD;
  float* vb   = ws + 4*TD;
  float* ao   = ws + 5*TD;
  float* hid  = ws + 2*TD;          // aliases qb..ao (TKF*1024 == 4*TD); used after attn+WO
  float* yb   = ws + 6*TD;          // 4*TD
  float* feat = ws + 10*TD;         // NBINTOT*64
  float* gate = feat + (size_t)NBINTOT*64;
  int* idx    = (int*)(gate + TKF);
  int* slot   = idx + TKF;
  int* rowmap = slot + TKF;
  int* cnt    = rowmap + NEXP*CAPACITY;
  int* msk    = cnt + 32;

  conv_frontend<<<NBINTOT, 64, 0, stream>>>(x, conv_w1, conv_w2, conv_w3,
      bn1_g, bn1_b, bn2_g, bn2_b, bn3_g, bn3_b, feat, msk);
  embed_kernel<<<dim3(SEQ, BATCH), 256, 0, stream>>>(feat, msk, proj_w, proj_b,
      cls_token, mask_tok, h);

  dim3 gdense((NTOK + 127)/128, 8);      // 33 x 8
  dim3 gmoe(NEXP*9, 8);                  // 270 x 8

  for (int l = 0; l < NLAYER; l++) {
    const float* wq_l = wq + (size_t)l*DMODEL*DMODEL;
    const float* wk_l = wk + (size_t)l*DMODEL*DMODEL;
    const float* wv_l = wv + (size_t)l*DMODEL*DMODEL;
    const float* wo_l = wo + (size_t)l*DMODEL*DMODEL;
    const float* we1_l = we1 + (size_t)l*NEXP*DMODEL*1024;
    const float* we2_l = we2 + (size_t)l*NEXP*1024*DMODEL;

    ln_kernel<<<NTOK, 256, 0, stream>>>(h, xbuf, ln1_g + (size_t)l*DMODEL, ln1_b + (size_t)l*DMODEL);
    gemm_bf16<0><<<gdense, 512, 0, stream>>>(xbuf, wq_l, bq + (size_t)l*DMODEL, qb, NTOK, nullptr, nullptr, nullptr);
    gemm_bf16<0><<<gdense, 512, 0, stream>>>(xbuf, wk_l, bk + (size_t)l*DMODEL, kb, NTOK, nullptr, nullptr, nullptr);
    gemm_bf16<0><<<gdense, 512, 0, stream>>>(xbuf, wv_l, bv + (size_t)l*DMODEL, vb, NTOK, nullptr, nullptr, nullptr);
    attn_tiled<<<dim3(9, BATCH*NHEAD), 256, 0, stream>>>(qb, kb, vb, ao);
    gemm_bf16<1><<<gdense, 512, 0, stream>>>(ao, wo_l, bo + (size_t)l*DMODEL, h, NTOK, nullptr, nullptr, nullptr);
    ln_kernel<<<NTOK, 256, 0, stream>>>(h, xbuf, ln2_g + (size_t)l*DMODEL, ln2_b + (size_t)l*DMODEL);
    moe_gate<<<NTOK, 256, 0, stream>>>(xbuf, wg + (size_t)l*DMODEL*NEXP, bg + (size_t)l*NEXP, idx, gate);
    moe_dispatch<<<NEXP, 256, 0, stream>>>(idx, slot, rowmap, cnt);
    gemm_bf16<2><<<gmoe, 512, 0, stream>>>(xbuf, we1_l, be1 + (size_t)l*NEXP*1024, hid, 0, rowmap, cnt, nullptr);
    gemm_bf16<3><<<gmoe, 512, 0, stream>>>(hid, we2_l, be2 + (size_t)l*NEXP*1024, yb, 0, rowmap, cnt, gate);
    moe_sum<<<NTOK, 256, 0, stream>>>(yb, slot, h);
  }
  final_copy<<<BATCH, 256, 0, stream>>>(h, out);
}

// Round 6
// 2999.909 us; speedup vs baseline: 4.3927x; 1.3201x over previous
//
#include <hip/hip_runtime.h>
#include <hip/hip_bf16.h>
#include <math.h>

#define BATCH   8
#define NBINS   512
#define BINSZ   10
#define DMODEL  1024
#define NHEAD   8
#define DHEAD   128
#define NLAYER  4
#define NEXP    30
#define TOPK    4
#define SEQ     513            // NBINS + 1
#define NTOK    (BATCH*SEQ)    // 4104
#define NBINTOT (BATCH*NBINS)  // 4096
#define CAPACITY 1152
#define TKF     (NTOK*TOPK)    // 16416

typedef __attribute__((ext_vector_type(8))) __bf16 bf16x8;
typedef __attribute__((ext_vector_type(4))) float f32x4;

__device__ __forceinline__ float gelu_f(float x) {
  return 0.5f * x * (1.0f + erff(x * 0.7071067811865475f));
}

// ---------------------------------------------------------------- conv frontend (named-scalar accs)
#define CSTEP(acc, T, DIL, hr, wA, wB, wC) { \
  float vv_ = (wB) * (hr)[T]; \
  if ((T) >= (DIL)) vv_ = fmaf((wA), (hr)[(T)-(DIL)], vv_); \
  if ((T) + (DIL) <= 9) vv_ = fmaf((wC), (hr)[(T)+(DIL)], vv_); \
  acc += vv_; }

#define CALL10(DIL, hr, wA, wB, wC) \
  CSTEP(t0,0,DIL,hr,wA,wB,wC); CSTEP(t1,1,DIL,hr,wA,wB,wC); \
  CSTEP(t2,2,DIL,hr,wA,wB,wC); CSTEP(t3,3,DIL,hr,wA,wB,wC); \
  CSTEP(t4,4,DIL,hr,wA,wB,wC); CSTEP(t5,5,DIL,hr,wA,wB,wC); \
  CSTEP(t6,6,DIL,hr,wA,wB,wC); CSTEP(t7,7,DIL,hr,wA,wB,wC); \
  CSTEP(t8,8,DIL,hr,wA,wB,wC); CSTEP(t9,9,DIL,hr,wA,wB,wC);

#define ZERO10 float t0=0.f,t1=0.f,t2=0.f,t3=0.f,t4=0.f,t5=0.f,t6=0.f,t7=0.f,t8=0.f,t9=0.f;

#define STORE10(dst, sc, sh) \
  (dst)[0]=gelu_f(t0*(sc)+(sh)); (dst)[1]=gelu_f(t1*(sc)+(sh)); \
  (dst)[2]=gelu_f(t2*(sc)+(sh)); (dst)[3]=gelu_f(t3*(sc)+(sh)); \
  (dst)[4]=gelu_f(t4*(sc)+(sh)); (dst)[5]=gelu_f(t5*(sc)+(sh)); \
  (dst)[6]=gelu_f(t6*(sc)+(sh)); (dst)[7]=gelu_f(t7*(sc)+(sh)); \
  (dst)[8]=gelu_f(t8*(sc)+(sh)); (dst)[9]=gelu_f(t9*(sc)+(sh));

__global__ __launch_bounds__(64) void conv_frontend(const float* __restrict__ x,
                              const float* __restrict__ w1, const float* __restrict__ w2,
                              const float* __restrict__ w3,
                              const float* __restrict__ g1, const float* __restrict__ b1,
                              const float* __restrict__ g2, const float* __restrict__ b2,
                              const float* __restrict__ g3, const float* __restrict__ b3,
                              float* __restrict__ feat, int* __restrict__ msk) {
  const float bnscale = 0.9999950000374997f;   // 1/sqrt(1+1e-5)
  int bin = blockIdx.x;
  int c = threadIdx.x;
  __shared__ float xs[BINSZ];
  __shared__ float h1[16][BINSZ];
  __shared__ float h2[32][BINSZ];
  if (c < BINSZ) xs[c] = x[bin*BINSZ + c];
  if (c == 0) {
    int all = 1;
    for (int t = 0; t < BINSZ; t++) if (x[bin*BINSZ+t] != -100.0f) { all = 0; break; }
    msk[bin] = all;
  }
  __syncthreads();
  if (c < 16) {
    float sc = g1[c]*bnscale, sh = b1[c];
    float wA = w1[c*3], wB = w1[c*3+1], wC = w1[c*3+2];
    const float* hr = &xs[0];
    ZERO10;
    CALL10(1, hr, wA, wB, wC);
    STORE10(&h1[c][0], sc, sh);
  }
  __syncthreads();
  if (c < 32) {
    float sc = g2[c]*bnscale, sh = b2[c];
    ZERO10;
    for (int ci = 0; ci < 16; ci++) {
      const float* w = w2 + (c*16+ci)*3;
      float wA = w[0], wB = w[1], wC = w[2];
      const float* hr = &h1[ci][0];
      CALL10(2, hr, wA, wB, wC);
    }
    STORE10(&h2[c][0], sc, sh);
  }
  __syncthreads();
  {
    float sc = g3[c]*bnscale, sh = b3[c];
    ZERO10;
    for (int ci = 0; ci < 32; ci++) {
      const float* w = w3 + (c*32+ci)*3;
      float wA = w[0], wB = w[1], wC = w[2];
      const float* hr = &h2[ci][0];
      CALL10(4, hr, wA, wB, wC);
    }
    float mean = gelu_f(t0*sc+sh) + gelu_f(t1*sc+sh) + gelu_f(t2*sc+sh)
               + gelu_f(t3*sc+sh) + gelu_f(t4*sc+sh) + gelu_f(t5*sc+sh)
               + gelu_f(t6*sc+sh) + gelu_f(t7*sc+sh) + gelu_f(t8*sc+sh)
               + gelu_f(t9*sc+sh);
    feat[bin*64 + c] = mean * 0.1f;
  }
}

// ---------------------------------------------------------------- embed + PE
__global__ void embed_kernel(const float* __restrict__ feat, const int* __restrict__ msk,
                             const float* __restrict__ proj_w, const float* __restrict__ proj_b,
                             const float* __restrict__ cls_token, const float* __restrict__ mask_token,
                             float* __restrict__ h) {
  int s_ = blockIdx.x;
  int b  = blockIdx.y;
  int tid = threadIdx.x;
  __shared__ __align__(16) float fs[64];
  float out[4];
  if (s_ == 0) {
#pragma unroll
    for (int u = 0; u < 4; u++) out[u] = cls_token[tid*4+u];
  } else {
    int bin = b*NBINS + (s_-1);
    if (tid < 16) ((float4*)fs)[tid] = ((const float4*)(feat + (size_t)bin*64))[tid];
    __syncthreads();
    int m_ = msk[bin];
#pragma unroll
    for (int u = 0; u < 4; u++) {
      int d = tid*4+u;
      float acc = proj_b[d];
      for (int ci = 0; ci < 64; ci++) acc = fmaf(fs[ci], proj_w[ci*DMODEL + d], acc);
      out[u] = m_ ? mask_token[d] : acc;
    }
  }
  const float c0 = -0.008994473019507992f;  // -ln(10000)/1024
#pragma unroll
  for (int u = 0; u < 4; u++) {
    int d = tid*4+u;
    float div = expf(c0 * (float)(d & ~1));
    float ang = (float)s_ * div;
    float pe = (d & 1) ? cosf(ang) : sinf(ang);
    h[((size_t)(b*SEQ + s_))*DMODEL + d] = out[u] + pe;
  }
}

// ---------------------------------------------------------------- layernorm
__global__ void ln_kernel(const float* __restrict__ x, float* __restrict__ out,
                          const float* __restrict__ g, const float* __restrict__ b) {
  int t = blockIdx.x, tid = threadIdx.x;
  float4 v = ((const float4*)(x + (size_t)t*DMODEL))[tid];
  float s  = v.x+v.y+v.z+v.w;
  float sq = v.x*v.x+v.y*v.y+v.z*v.z+v.w*v.w;
  for (int off = 32; off; off >>= 1) { s += __shfl_down(s, off); sq += __shfl_down(sq, off); }
  __shared__ float ss[4], ssq[4], mv[2];
  int w = tid >> 6, l = tid & 63;
  if (l == 0) { ss[w] = s; ssq[w] = sq; }
  __syncthreads();
  if (tid == 0) {
    float a = 0, c = 0;
    for (int i = 0; i < 4; i++) { a += ss[i]; c += ssq[i]; }
    float mean = a * (1.f/DMODEL);
    float var  = c * (1.f/DMODEL) - mean*mean;
    mv[0] = mean; mv[1] = rsqrtf(var + 1e-5f);
  }
  __syncthreads();
  float mean = mv[0], inv = mv[1];
  float4 gg = ((const float4*)g)[tid];
  float4 bb = ((const float4*)b)[tid];
  float4 o;
  o.x = (v.x-mean)*inv*gg.x + bb.x;
  o.y = (v.y-mean)*inv*gg.y + bb.y;
  o.z = (v.z-mean)*inv*gg.z + bb.z;
  o.w = (v.w-mean)*inv*gg.w + bb.w;
  ((float4*)(out + (size_t)t*DMODEL))[tid] = o;
}

// ---------------------------------------------------------------- bf16 MFMA GEMM, 128x128 tile
template<int MODE>
__global__ __launch_bounds__(512) void gemm_bf16(
    const float* __restrict__ A, const float* __restrict__ W,
    const float* __restrict__ bias, float* __restrict__ C, int M,
    const int* __restrict__ rowmap, const int* __restrict__ cnt,
    const float* __restrict__ gate) {
  int tid = threadIdx.x;
  int rowbase, validrows, e = 0;
  const float* Wb = W;
  if (MODE <= 1) {
    rowbase = blockIdx.x * 128;
    validrows = M - rowbase; if (validrows > 128) validrows = 128;
  } else {
    e = blockIdx.x / 9;
    int p0 = (blockIdx.x % 9) * 128;
    int ce = cnt[e];
    if (p0 >= ce) return;
    rowbase = p0;
    validrows = ce - p0; if (validrows > 128) validrows = 128;
    Wb = W + (size_t)e * 1024 * 1024;
  }
  int colbase = blockIdx.y * 128;

  __shared__ __align__(16) __bf16 As[4][128][8];   // [kgroup][row][8k]
  __shared__ __align__(16) __bf16 Bs[4][128][8];   // [kgroup][col][8k]
  __shared__ int srcrow[128];
  __shared__ int frow[128];

  if (tid < 128) {
    if (MODE <= 1) { srcrow[tid] = rowbase + tid; frow[tid] = rowbase + tid; }
    else if (tid < validrows) {
      int f = rowmap[e*CAPACITY + rowbase + tid];
      frow[tid] = f;
      srcrow[tid] = (MODE == 2) ? (f >> 2) : f;
    } else { frow[tid] = 0; srcrow[tid] = 0; }
  }
  __syncthreads();

  int arow = tid >> 2, ag = tid & 3;            // A: row, k-group (8 floats each)
  int wcol = tid & 127, wgp = tid >> 7;         // W: col, k-group
  bool aval = (arow < validrows);
  const float* Ap = A + (size_t)srcrow[arow] * 1024 + ag * 8;
  const float* Wp = Wb + (size_t)(wgp * 8) * 1024 + colbase + wcol;

  int w  = tid >> 6;
  int wr = w & 3, wc = w >> 2;        // wave quadrant: rows wr*32.., cols wc*64..
  int l  = tid & 63;
  int lr = l & 15, lg = l >> 4;

  f32x4 acc[2][4] = {};

  float4 a_lo = {}, a_hi = {};
  float wreg[8];
  if (aval) { a_lo = *(const float4*)(Ap); a_hi = *(const float4*)(Ap + 4); }
#pragma unroll
  for (int j = 0; j < 8; j++) wreg[j] = Wp[(size_t)j * 1024];

  for (int kt = 0; kt < 1024; kt += 32) {
    __syncthreads();
    bf16x8 av;
    av[0] = (__bf16)a_lo.x; av[1] = (__bf16)a_lo.y; av[2] = (__bf16)a_lo.z; av[3] = (__bf16)a_lo.w;
    av[4] = (__bf16)a_hi.x; av[5] = (__bf16)a_hi.y; av[6] = (__bf16)a_hi.z; av[7] = (__bf16)a_hi.w;
    *(bf16x8*)&As[ag][arow][0] = av;
    bf16x8 bv;
#pragma unroll
    for (int j = 0; j < 8; j++) bv[j] = (__bf16)wreg[j];
    *(bf16x8*)&Bs[wgp][wcol][0] = bv;
    __syncthreads();

    if (kt + 32 < 1024) {
      if (aval) {
        a_lo = *(const float4*)(Ap + kt + 32);
        a_hi = *(const float4*)(Ap + kt + 36);
      }
#pragma unroll
      for (int j = 0; j < 8; j++) wreg[j] = Wp[(size_t)(kt + 32 + j) * 1024];
    }

    bf16x8 af[2], bf[4];
    af[0] = *(const bf16x8*)&As[lg][wr*32 + lr][0];
    af[1] = *(const bf16x8*)&As[lg][wr*32 + 16 + lr][0];
#pragma unroll
    for (int fj = 0; fj < 4; fj++) bf[fj] = *(const bf16x8*)&Bs[lg][wc*64 + fj*16 + lr][0];
#pragma unroll
    for (int fi = 0; fi < 2; fi++)
#pragma unroll
      for (int fj = 0; fj < 4; fj++)
        acc[fi][fj] = __builtin_amdgcn_mfma_f32_16x16x32_bf16(af[fi], bf[fj], acc[fi][fj], 0, 0, 0);
  }

  const float* bptr = (MODE >= 2) ? (bias + (size_t)e * 1024) : bias;
#pragma unroll
  for (int fj = 0; fj < 4; fj++) {
    int col = wc*64 + fj*16 + lr;
    float bvv = bptr[colbase + col];
#pragma unroll
    for (int fi = 0; fi < 2; fi++) {
#pragma unroll
      for (int i = 0; i < 4; i++) {
        int r = wr*32 + fi*16 + lg*4 + i;
        if (r >= validrows) continue;
        float val = acc[fi][fj][i] + bvv;
        if (MODE == 0) {
          C[(size_t)(rowbase + r)*1024 + colbase + col] = val;
        } else if (MODE == 1) {
          float* p = C + (size_t)(rowbase + r)*1024 + colbase + col;
          *p = *p + val;
        } else if (MODE == 2) {
          C[(size_t)frow[r]*1024 + colbase + col] = gelu_f(val);
        } else {
          C[(size_t)frow[r]*1024 + colbase + col] = gate[frow[r]] * val;
        }
      }
    }
  }
}

// ---------------------------------------------------------------- MFMA flash attention
// grid (9 q-tiles, B*H); 256 threads = 4 waves; wave owns 16 q-rows.
// Swapped QK^T: S^T = K x Q^T so each lane's 16 S values belong to ONE q (col = lane&15).
// K: row-major bf16 LDS, XOR swizzle (row&7)<<4.  V: transposed LDS [d][kk] via
// column-gather staging (8 coalesced scalar loads -> 1 b128 write).  Q: registers.
__global__ __launch_bounds__(256) void attn_mfma(const float* __restrict__ q,
                                                 const float* __restrict__ k,
                                                 const float* __restrict__ v,
                                                 float* __restrict__ o) {
  int qt = blockIdx.x;
  int bh = blockIdx.y;
  int b = bh >> 3, hh = bh & 7;
  int tid = threadIdx.x;
  int wid = tid >> 6, l = tid & 63;
  int lr = l & 15, lg = l >> 4;

  __shared__ __align__(16) __bf16 Ks[64*128];   // [kk][d] row-major, swizzled
  __shared__ __align__(16) __bf16 Vt[128*64];   // [d][kk] row-major, swizzled

  const float scale = 0.08838834764831845f;  // 1/sqrt(128)

  // Q fragments (B operand): lane holds Q[q0w+lr][c*32 + lg*8 + j]
  int qtok = qt*64 + wid*16 + lr;
  int qtokc = qtok < SEQ ? qtok : SEQ-1;
  const float* qrow = q + ((size_t)(b*SEQ + qtokc))*DMODEL + hh*DHEAD;
  bf16x8 qf[4];
#pragma unroll
  for (int c = 0; c < 4; c++) {
    float4 x0 = *(const float4*)(qrow + c*32 + lg*8);
    float4 x1 = *(const float4*)(qrow + c*32 + lg*8 + 4);
    bf16x8 t;
    t[0]=(__bf16)x0.x; t[1]=(__bf16)x0.y; t[2]=(__bf16)x0.z; t[3]=(__bf16)x0.w;
    t[4]=(__bf16)x1.x; t[5]=(__bf16)x1.y; t[6]=(__bf16)x1.z; t[7]=(__bf16)x1.w;
    qf[c] = t;
  }

  float mreg = -1e30f, lsum = 0.f;
  f32x4 Oacc[8] = {};

  int krow = tid & 63, kdc = tid >> 6;   // K staging: row, 32-d chunk
  int vd = tid & 127, vkg0 = tid >> 7;   // V staging: d column, kk-group base

  for (int kt = 0; kt < 9; kt++) {
    int kt0 = kt*64;
    __syncthreads();
    // ---- stage K tile
    {
      int tok = kt0 + krow; if (tok >= SEQ) tok = SEQ-1;
      const float* kr = k + ((size_t)(b*SEQ + tok))*DMODEL + hh*DHEAD + kdc*32;
#pragma unroll
      for (int s2 = 0; s2 < 4; s2++) {
        float4 a0 = *(const float4*)(kr + s2*8);
        float4 a1 = *(const float4*)(kr + s2*8 + 4);
        bf16x8 t;
        t[0]=(__bf16)a0.x; t[1]=(__bf16)a0.y; t[2]=(__bf16)a0.z; t[3]=(__bf16)a0.w;
        t[4]=(__bf16)a1.x; t[5]=(__bf16)a1.y; t[6]=(__bf16)a1.z; t[7]=(__bf16)a1.w;
        int byte = (krow*256 + (kdc*32 + s2*8)*2) ^ ((krow & 7) << 4);
        *(bf16x8*)((char*)Ks + byte) = t;
      }
    }
    // ---- stage V^T (column gather)
    {
#pragma unroll
      for (int it = 0; it < 4; it++) {
        int kkg = vkg0 + it*2;
        bf16x8 t;
#pragma unroll
        for (int j = 0; j < 8; j++) {
          int tok = kt0 + kkg*8 + j; if (tok >= SEQ) tok = SEQ-1;
          t[j] = (__bf16)v[((size_t)(b*SEQ + tok))*DMODEL + hh*DHEAD + vd];
        }
        int byte = (vd*128 + kkg*16) ^ ((vd & 7) << 4);
        *(bf16x8*)((char*)Vt + byte) = t;
      }
    }
    __syncthreads();

    // ---- S^T = K x Q^T  (D[m=kk][n=q]), 4 kk-blocks x 4 d-chunks
    f32x4 sacc[4] = {};
#pragma unroll
    for (int c = 0; c < 4; c++) {
#pragma unroll
      for (int jb = 0; jb < 4; jb++) {
        int row = jb*16 + lr;
        int byte = (row*256 + (c*32 + lg*8)*2) ^ ((lr & 7) << 4);
        bf16x8 af = *(const bf16x8*)((const char*)Ks + byte);
        sacc[jb] = __builtin_amdgcn_mfma_f32_16x16x32_bf16(af, qf[c], sacc[jb], 0, 0, 0);
      }
    }

    // ---- online softmax; lane holds 16 kk values for q = qt*64 + wid*16 + lr
    float sv[4][4];
    float mt = -1e30f;
#pragma unroll
    for (int jb = 0; jb < 4; jb++)
#pragma unroll
      for (int i = 0; i < 4; i++) {
        int kkI = kt0 + jb*16 + lg*4 + i;
        float s = sacc[jb][i] * scale;
        if (kkI >= SEQ) s = -1e30f;
        sv[jb][i] = s;
        mt = fmaxf(mt, s);
      }
    mt = fmaxf(mt, __shfl_xor(mt, 16));
    mt = fmaxf(mt, __shfl_xor(mt, 32));
    float mnew = fmaxf(mreg, mt);
    float alpha = expf(mreg - mnew);
    float rs = 0.f;
#pragma unroll
    for (int jb = 0; jb < 4; jb++)
#pragma unroll
      for (int i = 0; i < 4; i++) {
        float p = expf(sv[jb][i] - mnew);
        sv[jb][i] = p; rs += p;
      }
    rs += __shfl_xor(rs, 16);
    rs += __shfl_xor(rs, 32);
    lsum = lsum * alpha + rs;
    mreg = mnew;

    // pack P -> bf16 pairs (u32), per acc-block
    unsigned pk[4][2];
#pragma unroll
    for (int jb = 0; jb < 4; jb++) {
      unsigned short c0 = __builtin_bit_cast(unsigned short, (__bf16)sv[jb][0]);
      unsigned short c1 = __builtin_bit_cast(unsigned short, (__bf16)sv[jb][1]);
      unsigned short c2 = __builtin_bit_cast(unsigned short, (__bf16)sv[jb][2]);
      unsigned short c3 = __builtin_bit_cast(unsigned short, (__bf16)sv[jb][3]);
      pk[jb][0] = ((unsigned)c1 << 16) | c0;
      pk[jb][1] = ((unsigned)c3 << 16) | c2;
    }

    // rescale O by alpha (alpha lives at lane lr=q; O rows q = lg*4+i)
    float al0 = __shfl(alpha, lg*4 + 0);
    float al1 = __shfl(alpha, lg*4 + 1);
    float al2 = __shfl(alpha, lg*4 + 2);
    float al3 = __shfl(alpha, lg*4 + 3);
#pragma unroll
    for (int db = 0; db < 8; db++) {
      Oacc[db][0] *= al0; Oacc[db][1] *= al1; Oacc[db][2] *= al2; Oacc[db][3] *= al3;
    }

    // ---- PV: build P A-fragments via shfl, multiply with V^T B-fragments
    int srcA = lr + ((lg & 1) << 5);
    int srcB = srcA + 16;
    bool hiSel = (lg >> 1) != 0;
#pragma unroll
    for (int c = 0; c < 2; c++) {
      int a00 = __shfl((int)pk[2*c][0], srcA);
      int a01 = __shfl((int)pk[2*c][1], srcA);
      int a10 = __shfl((int)pk[2*c+1][0], srcA);
      int a11 = __shfl((int)pk[2*c+1][1], srcA);
      int b00 = __shfl((int)pk[2*c][0], srcB);
      int b01 = __shfl((int)pk[2*c][1], srcB);
      int b10 = __shfl((int)pk[2*c+1][0], srcB);
      int b11 = __shfl((int)pk[2*c+1][1], srcB);
      int4 pa;
      pa.x = hiSel ? a10 : a00;
      pa.y = hiSel ? a11 : a01;
      pa.z = hiSel ? b10 : b00;
      pa.w = hiSel ? b11 : b01;
      bf16x8 paf = __builtin_bit_cast(bf16x8, pa);
#pragma unroll
      for (int db = 0; db < 8; db++) {
        int d = db*16 + lr;
        int byte = (d*128 + (c*32 + lg*8)*2) ^ ((lr & 7) << 4);
        bf16x8 bfv = *(const bf16x8*)((const char*)Vt + byte);
        Oacc[db] = __builtin_amdgcn_mfma_f32_16x16x32_bf16(paf, bfv, Oacc[db], 0, 0, 0);
      }
    }
  }

  // ---- epilogue: O rows q = lg*4+i, cols d = db*16+lr
  float l0 = __shfl(lsum, lg*4 + 0);
  float l1 = __shfl(lsum, lg*4 + 1);
  float l2 = __shfl(lsum, lg*4 + 2);
  float l3 = __shfl(lsum, lg*4 + 3);
  float inv[4] = {1.f/l0, 1.f/l1, 1.f/l2, 1.f/l3};
#pragma unroll
  for (int i = 0; i < 4; i++) {
    int tok = qt*64 + wid*16 + lg*4 + i;
    if (tok < SEQ) {
      float* dst = o + ((size_t)(b*SEQ + tok))*DMODEL + hh*DHEAD + lr;
#pragma unroll
      for (int db = 0; db < 8; db++) dst[db*16] = Oacc[db][i] * inv[i];
    }
  }
}

// ---------------------------------------------------------------- MoE gating (softmax + top-4)
__global__ void moe_gate(const float* __restrict__ m, const float* __restrict__ wg,
                         const float* __restrict__ bg, int* __restrict__ idx,
                         float* __restrict__ gate) {
  int t = blockIdx.x, tid = threadIdx.x;
  __shared__ __align__(16) float xs[DMODEL];
  __shared__ float probs[32];
  ((float4*)xs)[tid] = ((const float4*)(m + (size_t)t*DMODEL))[tid];
  __syncthreads();
  int e = tid >> 3, sub = tid & 7;
  if (e < NEXP) {
    float p = 0.f;
    for (int d = sub; d < DMODEL; d += 8) p = fmaf(xs[d], wg[d*NEXP + e], p);
    p += __shfl_down(p, 4, 8);
    p += __shfl_down(p, 2, 8);
    p += __shfl_down(p, 1, 8);
    if (sub == 0) probs[e] = p + bg[e];
  }
  __syncthreads();
  if (tid == 0) {
    float mx = probs[0];
    for (int i = 1; i < NEXP; i++) mx = fmaxf(mx, probs[i]);
    float ssum = 0.f;
    for (int i = 0; i < NEXP; i++) { probs[i] = expf(probs[i]-mx); ssum += probs[i]; }
    float invs = 1.f / ssum;
    float gv[TOPK]; int gi[TOPK]; float gsum = 0.f;
    for (int kk = 0; kk < TOPK; kk++) {
      float best = -1.f; int bi = 0;
      for (int i = 0; i < NEXP; i++) if (probs[i] > best) { best = probs[i]; bi = i; }
      gv[kk] = best * invs; gi[kk] = bi; probs[bi] = -1.f; gsum += gv[kk];
    }
    float ginv = 1.f / gsum;
    for (int kk = 0; kk < TOPK; kk++) { idx[t*TOPK+kk] = gi[kk]; gate[t*TOPK+kk] = gv[kk]*ginv; }
  }
}

// ---------------------------------------------------------------- MoE dispatch (ballot scan)
__global__ void moe_dispatch(const int* __restrict__ idx, int* __restrict__ slot,
                             int* __restrict__ rowmap, int* __restrict__ cnt) {
  int e = blockIdx.x, tid = threadIdx.x;
  int lane = tid & 63, wid = tid >> 6;
  __shared__ int wsum[4];
  int base = 0;
  for (int c0 = 0; c0 < TKF; c0 += 256) {
    int f = c0 + tid;
    int match = (f < TKF && idx[f] == e) ? 1 : 0;
    unsigned long long bal = __ballot(match);
    if (lane == 0) wsum[wid] = __popcll(bal);
    __syncthreads();
    int prefix = 0;
#pragma unroll
    for (int w2 = 0; w2 < 4; w2++) if (w2 < wid) prefix += wsum[w2];
    int total = wsum[0] + wsum[1] + wsum[2] + wsum[3];
    if (match) {
      int pos = base + prefix + __popcll(bal & ((1ull << lane) - 1ull));
      if (pos < CAPACITY) { slot[f] = pos; rowmap[e*CAPACITY + pos] = f; }
      else slot[f] = -1;
    }
    base += total;
    __syncthreads();
  }
  if (tid == 0) cnt[e] = (base < CAPACITY) ? base : CAPACITY;
}

// ---------------------------------------------------------------- MoE combine
__global__ void moe_sum(const float* __restrict__ y, const int* __restrict__ slot,
                        float* __restrict__ h) {
  int t = blockIdx.x, d4 = threadIdx.x;
  float4 acc = ((float4*)(h + (size_t)t*DMODEL))[d4];
#pragma unroll
  for (int kk = 0; kk < TOPK; kk++) {
    int f = t*TOPK + kk;
    if (slot[f] >= 0) {
      float4 yv = ((const float4*)(y + (size_t)f*DMODEL))[d4];
      acc.x += yv.x; acc.y += yv.y; acc.z += yv.z; acc.w += yv.w;
    }
  }
  ((float4*)(h + (size_t)t*DMODEL))[d4] = acc;
}

// ---------------------------------------------------------------- final output
__global__ void final_copy(const float* __restrict__ h, float* __restrict__ out) {
  int b = blockIdx.x, tid = threadIdx.x;
  float4 v = ((const float4*)(h + (size_t)b*SEQ*DMODEL))[tid];
  ((float4*)(out + (size_t)b*DMODEL))[tid] = v;
}

// ---------------------------------------------------------------- host
extern "C" void kernel_launch(void* const* d_in, const int* in_sizes, int n_in,
                              void* d_out, int out_size, void* d_ws, size_t ws_size,
                              hipStream_t stream) {
  (void)in_sizes; (void)n_in; (void)out_size; (void)ws_size;
  const float* x         = (const float*)d_in[0];
  const float* conv_w1   = (const float*)d_in[1];
  const float* conv_w2   = (const float*)d_in[2];
  const float* conv_w3   = (const float*)d_in[3];
  const float* bn1_g     = (const float*)d_in[4];
  const float* bn1_b     = (const float*)d_in[5];
  const float* bn2_g     = (const float*)d_in[6];
  const float* bn2_b     = (const float*)d_in[7];
  const float* bn3_g     = (const float*)d_in[8];
  const float* bn3_b     = (const float*)d_in[9];
  const float* proj_w    = (const float*)d_in[10];
  const float* proj_b    = (const float*)d_in[11];
  const float* cls_token = (const float*)d_in[12];
  const float* mask_tok  = (const float*)d_in[13];
  const float* ln1_g     = (const float*)d_in[14];
  const float* ln1_b     = (const float*)d_in[15];
  const float* ln2_g     = (const float*)d_in[16];
  const float* ln2_b     = (const float*)d_in[17];
  const float* wq        = (const float*)d_in[18];
  const float* wk        = (const float*)d_in[19];
  const float* wv        = (const float*)d_in[20];
  const float* wo        = (const float*)d_in[21];
  const float* bq        = (const float*)d_in[22];
  const float* bk        = (const float*)d_in[23];
  const float* bv        = (const float*)d_in[24];
  const float* bo        = (const float*)d_in[25];
  const float* wg        = (const float*)d_in[26];
  const float* bg        = (const float*)d_in[27];
  const float* we1       = (const float*)d_in[28];
  const float* be1       = (const float*)d_in[29];
  const float* we2       = (const float*)d_in[30];
  const float* be2       = (const float*)d_in[31];
  float* out = (float*)d_out;

  float* ws = (float*)d_ws;
  const size_t TD = (size_t)NTOK * DMODEL;   // 4,202,496 floats
  float* h    = ws;
  float* xbuf = ws + TD;
  float* qb   = ws + 2*TD;
  float* kb   = ws + 3*TD;
  float* vb   = ws + 4*TD;
  float* ao   = ws + 5*TD;
  float* hid  = ws + 2*TD;          // aliases qb..ao (TKF*1024 == 4*TD); used after attn+WO
  float* yb   = ws + 6*TD;          // 4*TD
  float* feat = ws + 10*TD;         // NBINTOT*64
  float* gate = feat + (size_t)NBINTOT*64;
  int* idx    = (int*)(gate + TKF);
  int* slot   = idx + TKF;
  int* rowmap = slot + TKF;
  int* cnt    = rowmap + NEXP*CAPACITY;
  int* msk    = cnt + 32;

  conv_frontend<<<NBINTOT, 64, 0, stream>>>(x, conv_w1, conv_w2, conv_w3,
      bn1_g, bn1_b, bn2_g, bn2_b, bn3_g, bn3_b, feat, msk);
  embed_kernel<<<dim3(SEQ, BATCH), 256, 0, stream>>>(feat, msk, proj_w, proj_b,
      cls_token, mask_tok, h);

  dim3 gdense((NTOK + 127)/128, 8);      // 33 x 8
  dim3 gmoe(NEXP*9, 8);                  // 270 x 8

  for (int l = 0; l < NLAYER; l++) {
    const float* wq_l = wq + (size_t)l*DMODEL*DMODEL;
    const float* wk_l = wk + (size_t)l*DMODEL*DMODEL;
    const float* wv_l = wv + (size_t)l*DMODEL*DMODEL;
    const float* wo_l = wo + (size_t)l*DMODEL*DMODEL;
    const float* we1_l = we1 + (size_t)l*NEXP*DMODEL*1024;
    const float* we2_l = we2 + (size_t)l*NEXP*1024*DMODEL;

    ln_kernel<<<NTOK, 256, 0, stream>>>(h, xbuf, ln1_g + (size_t)l*DMODEL, ln1_b + (size_t)l*DMODEL);
    gemm_bf16<0><<<gdense, 512, 0, stream>>>(xbuf, wq_l, bq + (size_t)l*DMODEL, qb, NTOK, nullptr, nullptr, nullptr);
    gemm_bf16<0><<<gdense, 512, 0, stream>>>(xbuf, wk_l, bk + (size_t)l*DMODEL, kb, NTOK, nullptr, nullptr, nullptr);
    gemm_bf16<0><<<gdense, 512, 0, stream>>>(xbuf, wv_l, bv + (size_t)l*DMODEL, vb, NTOK, nullptr, nullptr, nullptr);
    attn_mfma<<<dim3(9, BATCH*NHEAD), 256, 0, stream>>>(qb, kb, vb, ao);
    gemm_bf16<1><<<gdense, 512, 0, stream>>>(ao, wo_l, bo + (size_t)l*DMODEL, h, NTOK, nullptr, nullptr, nullptr);
    ln_kernel<<<NTOK, 256, 0, stream>>>(h, xbuf, ln2_g + (size_t)l*DMODEL, ln2_b + (size_t)l*DMODEL);
    moe_gate<<<NTOK, 256, 0, stream>>>(xbuf, wg + (size_t)l*DMODEL*NEXP, bg + (size_t)l*NEXP, idx, gate);
    moe_dispatch<<<NEXP, 256, 0, stream>>>(idx, slot, rowmap, cnt);
    gemm_bf16<2><<<gmoe, 512, 0, stream>>>(xbuf, we1_l, be1 + (size_t)l*NEXP*1024, hid, 0, rowmap, cnt, nullptr);
    gemm_bf16<3><<<gmoe, 512, 0, stream>>>(hid, we2_l, be2 + (size_t)l*NEXP*1024, yb, 0, rowmap, cnt, gate);
    moe_sum<<<NTOK, 256, 0, stream>>>(yb, slot, h);
  }
  final_copy<<<BATCH, 256, 0, stream>>>(h, out);
}

// Round 7
// 2778.383 us; speedup vs baseline: 4.7429x; 1.0797x over previous
//
#include <hip/hip_runtime.h>
#include <hip/hip_bf16.h>
#include <math.h>

#define BATCH   8
#define NBINS   512
#define BINSZ   10
#define DMODEL  1024
#define NHEAD   8
#define DHEAD   128
#define NLAYER  4
#define NEXP    30
#define TOPK    4
#define SEQ     513            // NBINS + 1
#define NTOK    (BATCH*SEQ)    // 4104
#define NBINTOT (BATCH*NBINS)  // 4096
#define CAPACITY 1152
#define TKF     (NTOK*TOPK)    // 16416

typedef __attribute__((ext_vector_type(8))) __bf16 bf16x8;
typedef __attribute__((ext_vector_type(4))) __bf16 bf16x4;
typedef __attribute__((ext_vector_type(4))) float f32x4;

__device__ __forceinline__ float gelu_f(float x) {
  return 0.5f * x * (1.0f + erff(x * 0.7071067811865475f));
}

__device__ __forceinline__ bf16x8 bf8_zero() {
  int4 z = make_int4(0, 0, 0, 0);
  return __builtin_bit_cast(bf16x8, z);
}

// ---------------------------------------------------------------- weight convert + transpose
// src: [nmat][1024][1024] fp32 row-major ([k][n]); dst: [nmat][1024][1024] bf16 ([n][k]).
// 64x64 tiles, 256 threads.
__global__ __launch_bounds__(256) void transpose_w(const float* __restrict__ src,
                                                   __bf16* __restrict__ dst) {
  int mat = blockIdx.y;
  int tile = blockIdx.x;          // 0..255
  int kt = (tile >> 4) * 64;
  int nt = (tile & 15) * 64;
  const float* s = src + (size_t)mat * 1024 * 1024;
  __bf16* d = dst + (size_t)mat * 1024 * 1024;
  __shared__ float t[64][65];
  int tid = threadIdx.x;
  int r = tid >> 4, c4 = (tid & 15) * 4;
#pragma unroll
  for (int i = 0; i < 4; i++) {
    float4 v = *(const float4*)(s + (size_t)(kt + r + i*16) * 1024 + nt + c4);
    t[r + i*16][c4+0] = v.x; t[r + i*16][c4+1] = v.y;
    t[r + i*16][c4+2] = v.z; t[r + i*16][c4+3] = v.w;
  }
  __syncthreads();
  int r2 = tid >> 2, c2 = (tid & 3) * 16;
  bf16x8 o0, o1;
#pragma unroll
  for (int j = 0; j < 8; j++) { o0[j] = (__bf16)t[c2+j][r2]; o1[j] = (__bf16)t[c2+8+j][r2]; }
  *(bf16x8*)(d + (size_t)(nt + r2) * 1024 + kt + c2)     = o0;
  *(bf16x8*)(d + (size_t)(nt + r2) * 1024 + kt + c2 + 8) = o1;
}

// ---------------------------------------------------------------- conv frontend (named-scalar accs)
#define CSTEP(acc, T, DIL, hr, wA, wB, wC) { \
  float vv_ = (wB) * (hr)[T]; \
  if ((T) >= (DIL)) vv_ = fmaf((wA), (hr)[(T)-(DIL)], vv_); \
  if ((T) + (DIL) <= 9) vv_ = fmaf((wC), (hr)[(T)+(DIL)], vv_); \
  acc += vv_; }

#define CALL10(DIL, hr, wA, wB, wC) \
  CSTEP(t0,0,DIL,hr,wA,wB,wC); CSTEP(t1,1,DIL,hr,wA,wB,wC); \
  CSTEP(t2,2,DIL,hr,wA,wB,wC); CSTEP(t3,3,DIL,hr,wA,wB,wC); \
  CSTEP(t4,4,DIL,hr,wA,wB,wC); CSTEP(t5,5,DIL,hr,wA,wB,wC); \
  CSTEP(t6,6,DIL,hr,wA,wB,wC); CSTEP(t7,7,DIL,hr,wA,wB,wC); \
  CSTEP(t8,8,DIL,hr,wA,wB,wC); CSTEP(t9,9,DIL,hr,wA,wB,wC);

#define ZERO10 float t0=0.f,t1=0.f,t2=0.f,t3=0.f,t4=0.f,t5=0.f,t6=0.f,t7=0.f,t8=0.f,t9=0.f;

#define STORE10(dst, sc, sh) \
  (dst)[0]=gelu_f(t0*(sc)+(sh)); (dst)[1]=gelu_f(t1*(sc)+(sh)); \
  (dst)[2]=gelu_f(t2*(sc)+(sh)); (dst)[3]=gelu_f(t3*(sc)+(sh)); \
  (dst)[4]=gelu_f(t4*(sc)+(sh)); (dst)[5]=gelu_f(t5*(sc)+(sh)); \
  (dst)[6]=gelu_f(t6*(sc)+(sh)); (dst)[7]=gelu_f(t7*(sc)+(sh)); \
  (dst)[8]=gelu_f(t8*(sc)+(sh)); (dst)[9]=gelu_f(t9*(sc)+(sh));

__global__ __launch_bounds__(64) void conv_frontend(const float* __restrict__ x,
                              const float* __restrict__ w1, const float* __restrict__ w2,
                              const float* __restrict__ w3,
                              const float* __restrict__ g1, const float* __restrict__ b1,
                              const float* __restrict__ g2, const float* __restrict__ b2,
                              const float* __restrict__ g3, const float* __restrict__ b3,
                              float* __restrict__ feat, int* __restrict__ msk) {
  const float bnscale = 0.9999950000374997f;   // 1/sqrt(1+1e-5)
  int bin = blockIdx.x;
  int c = threadIdx.x;
  __shared__ float xs[BINSZ];
  __shared__ float h1[16][BINSZ];
  __shared__ float h2[32][BINSZ];
  if (c < BINSZ) xs[c] = x[bin*BINSZ + c];
  if (c == 0) {
    int all = 1;
    for (int t = 0; t < BINSZ; t++) if (x[bin*BINSZ+t] != -100.0f) { all = 0; break; }
    msk[bin] = all;
  }
  __syncthreads();
  if (c < 16) {
    float sc = g1[c]*bnscale, sh = b1[c];
    float wA = w1[c*3], wB = w1[c*3+1], wC = w1[c*3+2];
    const float* hr = &xs[0];
    ZERO10;
    CALL10(1, hr, wA, wB, wC);
    STORE10(&h1[c][0], sc, sh);
  }
  __syncthreads();
  if (c < 32) {
    float sc = g2[c]*bnscale, sh = b2[c];
    ZERO10;
    for (int ci = 0; ci < 16; ci++) {
      const float* w = w2 + (c*16+ci)*3;
      float wA = w[0], wB = w[1], wC = w[2];
      const float* hr = &h1[ci][0];
      CALL10(2, hr, wA, wB, wC);
    }
    STORE10(&h2[c][0], sc, sh);
  }
  __syncthreads();
  {
    float sc = g3[c]*bnscale, sh = b3[c];
    ZERO10;
    for (int ci = 0; ci < 32; ci++) {
      const float* w = w3 + (c*32+ci)*3;
      float wA = w[0], wB = w[1], wC = w[2];
      const float* hr = &h2[ci][0];
      CALL10(4, hr, wA, wB, wC);
    }
    float mean = gelu_f(t0*sc+sh) + gelu_f(t1*sc+sh) + gelu_f(t2*sc+sh)
               + gelu_f(t3*sc+sh) + gelu_f(t4*sc+sh) + gelu_f(t5*sc+sh)
               + gelu_f(t6*sc+sh) + gelu_f(t7*sc+sh) + gelu_f(t8*sc+sh)
               + gelu_f(t9*sc+sh);
    feat[bin*64 + c] = mean * 0.1f;
  }
}

// ---------------------------------------------------------------- embed + PE
__global__ void embed_kernel(const float* __restrict__ feat, const int* __restrict__ msk,
                             const float* __restrict__ proj_w, const float* __restrict__ proj_b,
                             const float* __restrict__ cls_token, const float* __restrict__ mask_token,
                             float* __restrict__ h) {
  int s_ = blockIdx.x;
  int b  = blockIdx.y;
  int tid = threadIdx.x;
  __shared__ __align__(16) float fs[64];
  float out[4];
  if (s_ == 0) {
#pragma unroll
    for (int u = 0; u < 4; u++) out[u] = cls_token[tid*4+u];
  } else {
    int bin = b*NBINS + (s_-1);
    if (tid < 16) ((float4*)fs)[tid] = ((const float4*)(feat + (size_t)bin*64))[tid];
    __syncthreads();
    int m_ = msk[bin];
#pragma unroll
    for (int u = 0; u < 4; u++) {
      int d = tid*4+u;
      float acc = proj_b[d];
      for (int ci = 0; ci < 64; ci++) acc = fmaf(fs[ci], proj_w[ci*DMODEL + d], acc);
      out[u] = m_ ? mask_token[d] : acc;
    }
  }
  const float c0 = -0.008994473019507992f;  // -ln(10000)/1024
#pragma unroll
  for (int u = 0; u < 4; u++) {
    int d = tid*4+u;
    float div = expf(c0 * (float)(d & ~1));
    float ang = (float)s_ * div;
    float pe = (d & 1) ? cosf(ang) : sinf(ang);
    h[((size_t)(b*SEQ + s_))*DMODEL + d] = out[u] + pe;
  }
}

// ---------------------------------------------------------------- layernorm (fp32 out + bf16 out)
__global__ void ln_kernel(const float* __restrict__ x, float* __restrict__ out,
                          __bf16* __restrict__ outb,
                          const float* __restrict__ g, const float* __restrict__ b) {
  int t = blockIdx.x, tid = threadIdx.x;
  float4 v = ((const float4*)(x + (size_t)t*DMODEL))[tid];
  float s  = v.x+v.y+v.z+v.w;
  float sq = v.x*v.x+v.y*v.y+v.z*v.z+v.w*v.w;
  for (int off = 32; off; off >>= 1) { s += __shfl_down(s, off); sq += __shfl_down(sq, off); }
  __shared__ float ss[4], ssq[4], mv[2];
  int w = tid >> 6, l = tid & 63;
  if (l == 0) { ss[w] = s; ssq[w] = sq; }
  __syncthreads();
  if (tid == 0) {
    float a = 0, c = 0;
    for (int i = 0; i < 4; i++) { a += ss[i]; c += ssq[i]; }
    float mean = a * (1.f/DMODEL);
    float var  = c * (1.f/DMODEL) - mean*mean;
    mv[0] = mean; mv[1] = rsqrtf(var + 1e-5f);
  }
  __syncthreads();
  float mean = mv[0], inv = mv[1];
  float4 gg = ((const float4*)g)[tid];
  float4 bb = ((const float4*)b)[tid];
  float4 o;
  o.x = (v.x-mean)*inv*gg.x + bb.x;
  o.y = (v.y-mean)*inv*gg.y + bb.y;
  o.z = (v.z-mean)*inv*gg.z + bb.z;
  o.w = (v.w-mean)*inv*gg.w + bb.w;
  ((float4*)(out + (size_t)t*DMODEL))[tid] = o;
  bf16x4 ob;
  ob[0] = (__bf16)o.x; ob[1] = (__bf16)o.y; ob[2] = (__bf16)o.z; ob[3] = (__bf16)o.w;
  *(bf16x4*)(outb + (size_t)t*DMODEL + tid*4) = ob;
}

// ---------------------------------------------------------------- bf16 MFMA GEMM, 128x128 tile
// A: bf16 [rows][1024]; Wt: bf16 TRANSPOSED [n][k] per 1024x1024 matrix.
// MODE 0: C(bf16)[r] = A@W + bias           (QKV)
// MODE 1: C(f32)[r] += A@W + bias           (WO residual)
// MODE 2: hid(bf16)[f] = gelu(A[f>>2]@W_e + be)   (MoE ffn1, gather)
// MODE 3: y(f32)[f] = gate[f]*(A[f]@W_e + be)     (MoE ffn2)
template<int MODE>
__global__ __launch_bounds__(512) void gemm_bf16(
    const __bf16* __restrict__ A, const __bf16* __restrict__ Wt,
    const float* __restrict__ bias, void* __restrict__ C, int M,
    const int* __restrict__ rowmap, const int* __restrict__ cnt,
    const float* __restrict__ gate) {
  int tid = threadIdx.x;
  int rowbase, validrows, e = 0;
  const __bf16* Wb = Wt;
  if (MODE <= 1) {
    rowbase = blockIdx.x * 128;
    validrows = M - rowbase; if (validrows > 128) validrows = 128;
  } else {
    e = blockIdx.x / 9;
    int p0 = (blockIdx.x % 9) * 128;
    int ce = cnt[e];
    if (p0 >= ce) return;
    rowbase = p0;
    validrows = ce - p0; if (validrows > 128) validrows = 128;
    Wb = Wt + (size_t)e * 1024 * 1024;
  }
  int colbase = blockIdx.y * 128;

  __shared__ __align__(16) __bf16 As[4][128][8];   // [kgroup][row][8k]
  __shared__ __align__(16) __bf16 Bs[4][128][8];   // [kgroup][col][8k]
  __shared__ int srcrow[128];
  __shared__ int frow[128];

  if (tid < 128) {
    if (MODE <= 1) { srcrow[tid] = rowbase + tid; frow[tid] = rowbase + tid; }
    else if (tid < validrows) {
      int f = rowmap[e*CAPACITY + rowbase + tid];
      frow[tid] = f;
      srcrow[tid] = (MODE == 2) ? (f >> 2) : f;
    } else { frow[tid] = 0; srcrow[tid] = 0; }
  }
  __syncthreads();

  int arow = tid >> 2, ag = tid & 3;            // A: row, k-group (8 bf16 each)
  int wcol = tid & 127, wgp = tid >> 7;         // W: col, k-group
  bool aval = (arow < validrows);
  const __bf16* Ap = A + (size_t)srcrow[arow] * 1024 + ag * 8;
  const __bf16* Wp = Wb + (size_t)(colbase + wcol) * 1024 + wgp * 8;

  int w  = tid >> 6;
  int wr = w & 3, wc = w >> 2;        // wave quadrant: rows wr*32.., cols wc*64..
  int l  = tid & 63;
  int lr = l & 15, lg = l >> 4;

  f32x4 acc[2][4] = {};

  bf16x8 areg = bf8_zero(), breg;
  if (aval) areg = *(const bf16x8*)(Ap);
  breg = *(const bf16x8*)(Wp);

  for (int kt = 0; kt < 1024; kt += 32) {
    __syncthreads();
    *(bf16x8*)&As[ag][arow][0] = areg;
    *(bf16x8*)&Bs[wgp][wcol][0] = breg;
    __syncthreads();

    if (kt + 32 < 1024) {
      if (aval) areg = *(const bf16x8*)(Ap + kt + 32);
      breg = *(const bf16x8*)(Wp + kt + 32);
    }

    bf16x8 af[2], bf[4];
    af[0] = *(const bf16x8*)&As[lg][wr*32 + lr][0];
    af[1] = *(const bf16x8*)&As[lg][wr*32 + 16 + lr][0];
#pragma unroll
    for (int fj = 0; fj < 4; fj++) bf[fj] = *(const bf16x8*)&Bs[lg][wc*64 + fj*16 + lr][0];
#pragma unroll
    for (int fi = 0; fi < 2; fi++)
#pragma unroll
      for (int fj = 0; fj < 4; fj++)
        acc[fi][fj] = __builtin_amdgcn_mfma_f32_16x16x32_bf16(af[fi], bf[fj], acc[fi][fj], 0, 0, 0);
  }

  const float* bptr = (MODE >= 2) ? (bias + (size_t)e * 1024) : bias;
#pragma unroll
  for (int fj = 0; fj < 4; fj++) {
    int col = wc*64 + fj*16 + lr;
    float bvv = bptr[colbase + col];
#pragma unroll
    for (int fi = 0; fi < 2; fi++) {
#pragma unroll
      for (int i = 0; i < 4; i++) {
        int r = wr*32 + fi*16 + lg*4 + i;
        if (r >= validrows) continue;
        float val = acc[fi][fj][i] + bvv;
        if (MODE == 0) {
          ((__bf16*)C)[(size_t)(rowbase + r)*1024 + colbase + col] = (__bf16)val;
        } else if (MODE == 1) {
          float* p = (float*)C + (size_t)(rowbase + r)*1024 + colbase + col;
          *p = *p + val;
        } else if (MODE == 2) {
          ((__bf16*)C)[(size_t)frow[r]*1024 + colbase + col] = (__bf16)gelu_f(val);
        } else {
          ((float*)C)[(size_t)frow[r]*1024 + colbase + col] = gate[frow[r]] * val;
        }
      }
    }
  }
}

// ---------------------------------------------------------------- MFMA flash attention (bf16 in/out)
__global__ __launch_bounds__(256) void attn_mfma(const __bf16* __restrict__ q,
                                                 const __bf16* __restrict__ k,
                                                 const __bf16* __restrict__ v,
                                                 __bf16* __restrict__ o) {
  int qt = blockIdx.x;
  int bh = blockIdx.y;
  int b = bh >> 3, hh = bh & 7;
  int tid = threadIdx.x;
  int wid = tid >> 6, l = tid & 63;
  int lr = l & 15, lg = l >> 4;

  __shared__ __align__(16) __bf16 Ks[64*128];   // [kk][d] row-major, swizzled
  __shared__ __align__(16) __bf16 Vt[128*64];   // [d][kk] row-major, swizzled

  const float scale = 0.08838834764831845f;  // 1/sqrt(128)

  int qtok = qt*64 + wid*16 + lr;
  int qtokc = qtok < SEQ ? qtok : SEQ-1;
  const __bf16* qrow = q + ((size_t)(b*SEQ + qtokc))*DMODEL + hh*DHEAD;
  bf16x8 qf[4];
#pragma unroll
  for (int c = 0; c < 4; c++) qf[c] = *(const bf16x8*)(qrow + c*32 + lg*8);

  float mreg = -1e30f, lsum = 0.f;
  f32x4 Oacc[8] = {};

  int krow = tid & 63, kdc = tid >> 6;   // K staging: row, 32-d chunk
  int vd = tid & 127, vkg0 = tid >> 7;   // V staging: d column, kk-group base

  for (int kt = 0; kt < 9; kt++) {
    int kt0 = kt*64;
    __syncthreads();
    // ---- stage K tile (bf16 16B loads)
    {
      int tok = kt0 + krow; if (tok >= SEQ) tok = SEQ-1;
      const __bf16* kr = k + ((size_t)(b*SEQ + tok))*DMODEL + hh*DHEAD + kdc*32;
#pragma unroll
      for (int s2 = 0; s2 < 4; s2++) {
        bf16x8 t = *(const bf16x8*)(kr + s2*8);
        int byte = (krow*256 + (kdc*32 + s2*8)*2) ^ ((krow & 7) << 4);
        *(bf16x8*)((char*)Ks + byte) = t;
      }
    }
    // ---- stage V^T (column gather, 2B scalar loads)
    {
#pragma unroll
      for (int it = 0; it < 4; it++) {
        int kkg = vkg0 + it*2;
        bf16x8 t;
#pragma unroll
        for (int j = 0; j < 8; j++) {
          int tok = kt0 + kkg*8 + j; if (tok >= SEQ) tok = SEQ-1;
          t[j] = v[((size_t)(b*SEQ + tok))*DMODEL + hh*DHEAD + vd];
        }
        int byte = (vd*128 + kkg*16) ^ ((vd & 7) << 4);
        *(bf16x8*)((char*)Vt + byte) = t;
      }
    }
    __syncthreads();

    // ---- S^T = K x Q^T
    f32x4 sacc[4] = {};
#pragma unroll
    for (int c = 0; c < 4; c++) {
#pragma unroll
      for (int jb = 0; jb < 4; jb++) {
        int row = jb*16 + lr;
        int byte = (row*256 + (c*32 + lg*8)*2) ^ ((lr & 7) << 4);
        bf16x8 af = *(const bf16x8*)((const char*)Ks + byte);
        sacc[jb] = __builtin_amdgcn_mfma_f32_16x16x32_bf16(af, qf[c], sacc[jb], 0, 0, 0);
      }
    }

    // ---- online softmax
    float sv[4][4];
    float mt = -1e30f;
#pragma unroll
    for (int jb = 0; jb < 4; jb++)
#pragma unroll
      for (int i = 0; i < 4; i++) {
        int kkI = kt0 + jb*16 + lg*4 + i;
        float s = sacc[jb][i] * scale;
        if (kkI >= SEQ) s = -1e30f;
        sv[jb][i] = s;
        mt = fmaxf(mt, s);
      }
    mt = fmaxf(mt, __shfl_xor(mt, 16));
    mt = fmaxf(mt, __shfl_xor(mt, 32));
    float mnew = fmaxf(mreg, mt);
    float alpha = expf(mreg - mnew);
    float rs = 0.f;
#pragma unroll
    for (int jb = 0; jb < 4; jb++)
#pragma unroll
      for (int i = 0; i < 4; i++) {
        float p = expf(sv[jb][i] - mnew);
        sv[jb][i] = p; rs += p;
      }
    rs += __shfl_xor(rs, 16);
    rs += __shfl_xor(rs, 32);
    lsum = lsum * alpha + rs;
    mreg = mnew;

    unsigned pk[4][2];
#pragma unroll
    for (int jb = 0; jb < 4; jb++) {
      unsigned short c0 = __builtin_bit_cast(unsigned short, (__bf16)sv[jb][0]);
      unsigned short c1 = __builtin_bit_cast(unsigned short, (__bf16)sv[jb][1]);
      unsigned short c2 = __builtin_bit_cast(unsigned short, (__bf16)sv[jb][2]);
      unsigned short c3 = __builtin_bit_cast(unsigned short, (__bf16)sv[jb][3]);
      pk[jb][0] = ((unsigned)c1 << 16) | c0;
      pk[jb][1] = ((unsigned)c3 << 16) | c2;
    }

    float al0 = __shfl(alpha, lg*4 + 0);
    float al1 = __shfl(alpha, lg*4 + 1);
    float al2 = __shfl(alpha, lg*4 + 2);
    float al3 = __shfl(alpha, lg*4 + 3);
#pragma unroll
    for (int db = 0; db < 8; db++) {
      Oacc[db][0] *= al0; Oacc[db][1] *= al1; Oacc[db][2] *= al2; Oacc[db][3] *= al3;
    }

    int srcA = lr + ((lg & 1) << 5);
    int srcB = srcA + 16;
    bool hiSel = (lg >> 1) != 0;
#pragma unroll
    for (int c = 0; c < 2; c++) {
      int a00 = __shfl((int)pk[2*c][0], srcA);
      int a01 = __shfl((int)pk[2*c][1], srcA);
      int a10 = __shfl((int)pk[2*c+1][0], srcA);
      int a11 = __shfl((int)pk[2*c+1][1], srcA);
      int b00 = __shfl((int)pk[2*c][0], srcB);
      int b01 = __shfl((int)pk[2*c][1], srcB);
      int b10 = __shfl((int)pk[2*c+1][0], srcB);
      int b11 = __shfl((int)pk[2*c+1][1], srcB);
      int4 pa;
      pa.x = hiSel ? a10 : a00;
      pa.y = hiSel ? a11 : a01;
      pa.z = hiSel ? b10 : b00;
      pa.w = hiSel ? b11 : b01;
      bf16x8 paf = __builtin_bit_cast(bf16x8, pa);
#pragma unroll
      for (int db = 0; db < 8; db++) {
        int d = db*16 + lr;
        int byte = (d*128 + (c*32 + lg*8)*2) ^ ((lr & 7) << 4);
        bf16x8 bfv = *(const bf16x8*)((const char*)Vt + byte);
        Oacc[db] = __builtin_amdgcn_mfma_f32_16x16x32_bf16(paf, bfv, Oacc[db], 0, 0, 0);
      }
    }
  }

  float l0 = __shfl(lsum, lg*4 + 0);
  float l1 = __shfl(lsum, lg*4 + 1);
  float l2 = __shfl(lsum, lg*4 + 2);
  float l3 = __shfl(lsum, lg*4 + 3);
  float inv[4] = {1.f/l0, 1.f/l1, 1.f/l2, 1.f/l3};
#pragma unroll
  for (int i = 0; i < 4; i++) {
    int tok = qt*64 + wid*16 + lg*4 + i;
    if (tok < SEQ) {
      __bf16* dst = o + ((size_t)(b*SEQ + tok))*DMODEL + hh*DHEAD + lr;
#pragma unroll
      for (int db = 0; db < 8; db++) dst[db*16] = (__bf16)(Oacc[db][i] * inv[i]);
    }
  }
}

// ---------------------------------------------------------------- MoE gating (softmax + top-4)
__global__ void moe_gate(const float* __restrict__ m, const float* __restrict__ wg,
                         const float* __restrict__ bg, int* __restrict__ idx,
                         float* __restrict__ gate) {
  int t = blockIdx.x, tid = threadIdx.x;
  __shared__ __align__(16) float xs[DMODEL];
  __shared__ float probs[32];
  ((float4*)xs)[tid] = ((const float4*)(m + (size_t)t*DMODEL))[tid];
  __syncthreads();
  int e = tid >> 3, sub = tid & 7;
  if (e < NEXP) {
    float p = 0.f;
    for (int d = sub; d < DMODEL; d += 8) p = fmaf(xs[d], wg[d*NEXP + e], p);
    p += __shfl_down(p, 4, 8);
    p += __shfl_down(p, 2, 8);
    p += __shfl_down(p, 1, 8);
    if (sub == 0) probs[e] = p + bg[e];
  }
  __syncthreads();
  if (tid == 0) {
    float mx = probs[0];
    for (int i = 1; i < NEXP; i++) mx = fmaxf(mx, probs[i]);
    float ssum = 0.f;
    for (int i = 0; i < NEXP; i++) { probs[i] = expf(probs[i]-mx); ssum += probs[i]; }
    float invs = 1.f / ssum;
    float gv[TOPK]; int gi[TOPK]; float gsum = 0.f;
    for (int kk = 0; kk < TOPK; kk++) {
      float best = -1.f; int bi = 0;
      for (int i = 0; i < NEXP; i++) if (probs[i] > best) { best = probs[i]; bi = i; }
      gv[kk] = best * invs; gi[kk] = bi; probs[bi] = -1.f; gsum += gv[kk];
    }
    float ginv = 1.f / gsum;
    for (int kk = 0; kk < TOPK; kk++) { idx[t*TOPK+kk] = gi[kk]; gate[t*TOPK+kk] = gv[kk]*ginv; }
  }
}

// ---------------------------------------------------------------- MoE dispatch (ballot scan)
__global__ void moe_dispatch(const int* __restrict__ idx, int* __restrict__ slot,
                             int* __restrict__ rowmap, int* __restrict__ cnt) {
  int e = blockIdx.x, tid = threadIdx.x;
  int lane = tid & 63, wid = tid >> 6;
  __shared__ int wsum[4];
  int base = 0;
  for (int c0 = 0; c0 < TKF; c0 += 256) {
    int f = c0 + tid;
    int match = (f < TKF && idx[f] == e) ? 1 : 0;
    unsigned long long bal = __ballot(match);
    if (lane == 0) wsum[wid] = __popcll(bal);
    __syncthreads();
    int prefix = 0;
#pragma unroll
    for (int w2 = 0; w2 < 4; w2++) if (w2 < wid) prefix += wsum[w2];
    int total = wsum[0] + wsum[1] + wsum[2] + wsum[3];
    if (match) {
      int pos = base + prefix + __popcll(bal & ((1ull << lane) - 1ull));
      if (pos < CAPACITY) { slot[f] = pos; rowmap[e*CAPACITY + pos] = f; }
      else slot[f] = -1;
    }
    base += total;
    __syncthreads();
  }
  if (tid == 0) cnt[e] = (base < CAPACITY) ? base : CAPACITY;
}

// ---------------------------------------------------------------- MoE combine
__global__ void moe_sum(const float* __restrict__ y, const int* __restrict__ slot,
                        float* __restrict__ h) {
  int t = blockIdx.x, d4 = threadIdx.x;
  float4 acc = ((float4*)(h + (size_t)t*DMODEL))[d4];
#pragma unroll
  for (int kk = 0; kk < TOPK; kk++) {
    int f = t*TOPK + kk;
    if (slot[f] >= 0) {
      float4 yv = ((const float4*)(y + (size_t)f*DMODEL))[d4];
      acc.x += yv.x; acc.y += yv.y; acc.z += yv.z; acc.w += yv.w;
    }
  }
  ((float4*)(h + (size_t)t*DMODEL))[d4] = acc;
}

// ---------------------------------------------------------------- final output
__global__ void final_copy(const float* __restrict__ h, float* __restrict__ out) {
  int b = blockIdx.x, tid = threadIdx.x;
  float4 v = ((const float4*)(h + (size_t)b*SEQ*DMODEL))[tid];
  ((float4*)(out + (size_t)b*DMODEL))[tid] = v;
}

// ---------------------------------------------------------------- host
extern "C" void kernel_launch(void* const* d_in, const int* in_sizes, int n_in,
                              void* d_out, int out_size, void* d_ws, size_t ws_size,
                              hipStream_t stream) {
  (void)in_sizes; (void)n_in; (void)out_size; (void)ws_size;
  const float* x         = (const float*)d_in[0];
  const float* conv_w1   = (const float*)d_in[1];
  const float* conv_w2   = (const float*)d_in[2];
  const float* conv_w3   = (const float*)d_in[3];
  const float* bn1_g     = (const float*)d_in[4];
  const float* bn1_b     = (const float*)d_in[5];
  const float* bn2_g     = (const float*)d_in[6];
  const float* bn2_b     = (const float*)d_in[7];
  const float* bn3_g     = (const float*)d_in[8];
  const float* bn3_b     = (const float*)d_in[9];
  const float* proj_w    = (const float*)d_in[10];
  const float* proj_b    = (const float*)d_in[11];
  const float* cls_token = (const float*)d_in[12];
  const float* mask_tok  = (const float*)d_in[13];
  const float* ln1_g     = (const float*)d_in[14];
  const float* ln1_b     = (const float*)d_in[15];
  const float* ln2_g     = (const float*)d_in[16];
  const float* ln2_b     = (const float*)d_in[17];
  const float* wq        = (const float*)d_in[18];
  const float* wk        = (const float*)d_in[19];
  const float* wv        = (const float*)d_in[20];
  const float* wo        = (const float*)d_in[21];
  const float* bq        = (const float*)d_in[22];
  const float* bk        = (const float*)d_in[23];
  const float* bv        = (const float*)d_in[24];
  const float* bo        = (const float*)d_in[25];
  const float* wg        = (const float*)d_in[26];
  const float* bg        = (const float*)d_in[27];
  const float* we1       = (const float*)d_in[28];
  const float* be1       = (const float*)d_in[29];
  const float* we2       = (const float*)d_in[30];
  const float* be2       = (const float*)d_in[31];
  float* out = (float*)d_out;

  char* base = (char*)d_ws;
  const size_t TDB = (size_t)NTOK * DMODEL * 4;         // 16.8 MB
  float*  h    = (float*)(base);                        // 1 TDB
  float*  xbuf = (float*)(base + TDB);                  // 1 TDB
  float*  yb   = (float*)(base + 2*TDB);                // 4 TDB (TKF*1024 f32)
  __bf16* xbf  = (__bf16*)(base + 6*TDB);               // 0.5 TDB
  __bf16* qb   = (__bf16*)(base + 6*TDB + TDB/2);
  __bf16* kb   = (__bf16*)(base + 7*TDB);
  __bf16* vb   = (__bf16*)(base + 7*TDB + TDB/2);
  __bf16* ao   = (__bf16*)(base + 8*TDB);
  __bf16* hid  = (__bf16*)(base + 8*TDB + TDB/2);       // 2 TDB (TKF*1024 bf16)
  char* misc   = base + 11*TDB;
  float* feat  = (float*)misc;                          // NBINTOT*64
  float* gate  = feat + (size_t)NBINTOT*64;
  int* idx     = (int*)(gate + TKF);
  int* slot    = idx + TKF;
  int* rowmap  = slot + TKF;
  int* cnt     = rowmap + NEXP*CAPACITY;
  int* msk     = cnt + 32;
  char* wtb    = base + 12*TDB;                          // weight area
  const size_t MB1 = (size_t)1024*1024;                  // elems per matrix
  __bf16* wtq  = (__bf16*)wtb;                           // 4 mats
  __bf16* wtk  = wtq + 4*MB1;
  __bf16* wtv  = wtk + 4*MB1;
  __bf16* wto  = wtv + 4*MB1;
  __bf16* wte1 = wto + 4*MB1;                            // 120 mats
  __bf16* wte2 = wte1 + 120*MB1;                         // 120 mats

  // ---- one-time (per launch) weight convert+transpose to bf16 [n][k]
  transpose_w<<<dim3(256, 4),   256, 0, stream>>>(wq,  wtq);
  transpose_w<<<dim3(256, 4),   256, 0, stream>>>(wk,  wtk);
  transpose_w<<<dim3(256, 4),   256, 0, stream>>>(wv,  wtv);
  transpose_w<<<dim3(256, 4),   256, 0, stream>>>(wo,  wto);
  transpose_w<<<dim3(256, 120), 256, 0, stream>>>(we1, wte1);
  transpose_w<<<dim3(256, 120), 256, 0, stream>>>(we2, wte2);

  conv_frontend<<<NBINTOT, 64, 0, stream>>>(x, conv_w1, conv_w2, conv_w3,
      bn1_g, bn1_b, bn2_g, bn2_b, bn3_g, bn3_b, feat, msk);
  embed_kernel<<<dim3(SEQ, BATCH), 256, 0, stream>>>(feat, msk, proj_w, proj_b,
      cls_token, mask_tok, h);

  dim3 gdense((NTOK + 127)/128, 8);      // 33 x 8
  dim3 gmoe(NEXP*9, 8);                  // 270 x 8

  for (int l = 0; l < NLAYER; l++) {
    for (int z = 0; z < 1; z++) {}  // (no-op; keep structure)
    __bf16* wtq_l = wtq + (size_t)l*MB1;
    __bf16* wtk_l = wtk + (size_t)l*MB1;
    __bf16* wtv_l = wtv + (size_t)l*MB1;
    __bf16* wto_l = wto + (size_t)l*MB1;
    __bf16* wte1_l = wte1 + (size_t)l*NEXP*MB1;
    __bf16* wte2_l = wte2 + (size_t)l*NEXP*MB1;

    ln_kernel<<<NTOK, 256, 0, stream>>>(h, xbuf, xbf, ln1_g + (size_t)l*DMODEL, ln1_b + (size_t)l*DMODEL);
    gemm_bf16<0><<<gdense, 512, 0, stream>>>(xbf, wtq_l, bq + (size_t)l*DMODEL, qb, NTOK, nullptr, nullptr, nullptr);
    gemm_bf16<0><<<gdense, 512, 0, stream>>>(xbf, wtk_l, bk + (size_t)l*DMODEL, kb, NTOK, nullptr, nullptr, nullptr);
    gemm_bf16<0><<<gdense, 512, 0, stream>>>(xbf, wtv_l, bv + (size_t)l*DMODEL, vb, NTOK, nullptr, nullptr, nullptr);
    attn_mfma<<<dim3(9, BATCH*NHEAD), 256, 0, stream>>>(qb, kb, vb, ao);
    gemm_bf16<1><<<gdense, 512, 0, stream>>>(ao, wto_l, bo + (size_t)l*DMODEL, h, NTOK, nullptr, nullptr, nullptr);
    ln_kernel<<<NTOK, 256, 0, stream>>>(h, xbuf, xbf, ln2_g + (size_t)l*DMODEL, ln2_b + (size_t)l*DMODEL);
    moe_gate<<<NTOK, 256, 0, stream>>>(xbuf, wg + (size_t)l*DMODEL*NEXP, bg + (size_t)l*NEXP, idx, gate);
    moe_dispatch<<<NEXP, 256, 0, stream>>>(idx, slot, rowmap, cnt);
    gemm_bf16<2><<<gmoe, 512, 0, stream>>>(xbf, wte1_l, be1 + (size_t)l*NEXP*1024, hid, 0, rowmap, cnt, nullptr);
    gemm_bf16<3><<<gmoe, 512, 0, stream>>>(hid, wte2_l, be2 + (size_t)l*NEXP*1024, yb, 0, rowmap, cnt, gate);
    moe_sum<<<NTOK, 256, 0, stream>>>(yb, slot, h);
  }
  final_copy<<<BATCH, 256, 0, stream>>>(h, out);
}